// Round 1
// baseline (21748.660 us; speedup 1.0000x reference)
//
#include <hip/hip_runtime.h>
#include <math.h>

// Persistent-kernel NTM: 256 blocks x 256 threads, memory matrix resident in LDS
// (64 rows x 256 cols x fp32 = 64KB per block), custom device-scope grid barrier.
// 7 grid barriers per timestep x 128 steps.

#define NBLK 256
#define NTHR 256
#define Msz  16384
#define Dsz  256
#define Hsz  512
#define Isz  256
#define Tlen 128
#define RPB  64   // memory rows per block

struct Params {
  const float* in[34];
  float* out;
  float* ws;
};

__device__ __forceinline__ float wred64(float v){
#pragma unroll
  for (int o = 32; o > 0; o >>= 1) v += __shfl_xor(v, o, 64);
  return v;
}
__device__ __forceinline__ float wred32(float v){
#pragma unroll
  for (int o = 16; o > 0; o >>= 1) v += __shfl_xor(v, o, 32);
  return v;
}
__device__ __forceinline__ float sigm(float x){ return 1.f / (1.f + __expf(-x)); }
__device__ __forceinline__ float softplusf(float x){ return (x > 20.f) ? x : log1pf(__expf(x)); }

__global__ void __launch_bounds__(NTHR, 1)
ntm_kernel(Params P)
{
  const int b   = blockIdx.x;
  const int tid = threadIdx.x;
  const int wv  = tid >> 6;   // wave 0..3
  const int ln  = tid & 63;   // lane 0..63

  // ------- input pointers (setup_inputs dict order) -------
  const float* inputs  = P.in[0];
  const float* mem0    = P.in[1];
  const float* read_w0 = P.in[2];
  const float* write_w0= P.in[3];
  const float* W_ih = P.in[4];
  const float* W_hh = P.in[5];
  const float* b_ih = P.in[6];
  const float* b_hh = P.in[7];
  const float* Wo   = P.in[8];
  const float* bo   = P.in[9];
  const float* r_Wk = P.in[10]; const float* r_bk = P.in[11];
  const float* r_Wb = P.in[12]; const float* r_bb = P.in[13];
  const float* r_Wg = P.in[14]; const float* r_bg = P.in[15];
  const float* r_Ws = P.in[16]; const float* r_bs = P.in[17];
  const float* r_Wp = P.in[18]; const float* r_bp = P.in[19];
  const float* w_Wk = P.in[20]; const float* w_bk = P.in[21];
  const float* w_Wb = P.in[22]; const float* w_bb = P.in[23];
  const float* w_Wg = P.in[24]; const float* w_bg = P.in[25];
  const float* w_Ws = P.in[26]; const float* w_bs = P.in[27];
  const float* w_Wp = P.in[28]; const float* w_bp = P.in[29];
  const float* w_We = P.in[30]; const float* w_be = P.in[31];
  const float* w_Wa = P.in[32]; const float* w_ba = P.in[33];
  float* out = P.out;

  // ------- global scratch layout (floats) -------
  float* ws    = P.ws;
  float* rw    = ws;                 // M   read weights
  float* wwv   = ws + Msz;           // M   write weights
  float* buf_e = ws + 2*Msz;         // M   exp(score) buffer (both heads, reused)
  float* harr  = ws + 3*Msz;         // 2*H h double buffer
  float* keyw  = harr + 2*Hsz;       // 256
  float* keyr  = keyw + 256;         // 256
  float* ersv  = keyr + 256;         // 256 (post-sigmoid erase)
  float* addv  = ersv + 256;         // 256
  float* rvec  = addv + 256;         // 256 read vector (atomic accumulator)
  float* scal  = rvec + 256;         // 16 raw head scalars
  float* psA   = scal + 16;          // 256 per-block partial sums (e)
  float* psB   = psA + 256;          // 256 per-block partial sums (w)
  unsigned int* sy = (unsigned int*)(psB + 256); // cnt, gen, flag

  unsigned int* cnt = sy;
  unsigned int* gen = sy + 1;
  unsigned int* flg = sy + 2;

  // ------- LDS -------
  __shared__ float s_mem[RPB * Dsz];   // 64KB: this block's memory rows
  __shared__ float s_co[Hsz];          // staged h/co
  __shared__ float s_a[256], s_b[256], s_c[256];
  __shared__ float s_norm[RPB];        // row norms
  __shared__ float s_bw[RPB];          // sharpened (unnormalized) weights
  __shared__ float s_red[4];
  __shared__ float s_lg[8];
  __shared__ float s_wsum[4];
  __shared__ float s_cst[2];           // LSTM cell state (this block's 2 hidden units)

  // ------- sync-var init (ws is poisoned 0xAA each launch) -------
  if (b == 0 && tid == 0){
    __hip_atomic_store(cnt, 0u, __ATOMIC_RELAXED, __HIP_MEMORY_SCOPE_AGENT);
    __hip_atomic_store(gen, 0u, __ATOMIC_RELAXED, __HIP_MEMORY_SCOPE_AGENT);
    __hip_atomic_store(flg, 0xC0FFEEu, __ATOMIC_RELEASE, __HIP_MEMORY_SCOPE_AGENT);
  }
  if (tid == 0){
    while (__hip_atomic_load(flg, __ATOMIC_ACQUIRE, __HIP_MEMORY_SCOPE_AGENT) != 0xC0FFEEu)
      __builtin_amdgcn_s_sleep(1);
  }
  __syncthreads();

  auto gbar = [&](){
    __syncthreads();
    if (tid == 0){
      __threadfence();   // release: flush this XCD's L2 so other XCDs see our writes
      unsigned int g = __hip_atomic_load(gen, __ATOMIC_RELAXED, __HIP_MEMORY_SCOPE_AGENT);
      unsigned int p = __hip_atomic_fetch_add(cnt, 1u, __ATOMIC_ACQ_REL, __HIP_MEMORY_SCOPE_AGENT);
      if (p == NBLK - 1u){
        __hip_atomic_store(cnt, 0u, __ATOMIC_RELAXED, __HIP_MEMORY_SCOPE_AGENT);
        __hip_atomic_fetch_add(gen, 1u, __ATOMIC_RELEASE, __HIP_MEMORY_SCOPE_AGENT);
      } else {
        while (__hip_atomic_load(gen, __ATOMIC_RELAXED, __HIP_MEMORY_SCOPE_AGENT) == g)
          __builtin_amdgcn_s_sleep(1);
      }
      __threadfence();   // acquire: invalidate stale cached lines
    }
    __syncthreads();
  };

  auto bred256 = [&](float v)->float{
    v = wred64(v);
    __syncthreads();
    if (ln == 0) s_red[wv] = v;
    __syncthreads();
    return s_red[0] + s_red[1] + s_red[2] + s_red[3];
  };

  // shift + sharpen for one head: reads psA (e-sums), buf_e, prevw, scal[si..si+5];
  // writes s_bw (this block's rows) and psB[b] (sum of sharpened weights).
  auto shiftSharpen = [&](int si, const float* prevw){
    float S = bred256(psA[tid]);
    float g     = sigm(scal[si + 1]);
    float gamma = softplusf(scal[si + 2]) + 1.f;
    float a0 = scal[si + 3], a1 = scal[si + 4], a2 = scal[si + 5];
    float mx = fmaxf(a0, fmaxf(a1, a2));
    float e0 = __expf(a0 - mx), e1 = __expf(a1 - mx), e2 = __expf(a2 - mx);
    float idn = 1.f / (e0 + e1 + e2);
    float s0 = e0 * idn, s1 = e1 * idn, s2 = e2 * idn;
    float invS = 1.f / S;
    float w = 0.f;
    if (tid < RPB){
      int m  = b * RPB + tid;
      int mp = (m + 1) & (Msz - 1);
      int mm = (m - 1) & (Msz - 1);
      float gc = g * invS, gp = 1.f - g;
      float gwm = gc * buf_e[m]  + gp * prevw[m];
      float gw1 = gc * buf_e[mp] + gp * prevw[mp];   // roll(gw,-1)[m] = gw[m+1]
      float gw2 = gc * buf_e[mm] + gp * prevw[mm];   // roll(gw,+1)[m] = gw[m-1]
      float sh = s0 * gw1 + s1 * gwm + s2 * gw2;
      w = powf(sh, gamma);
      s_bw[tid] = w;
    }
    float tot = wred64(w);          // wave0 sums all 64 row values
    if (tid == 0) psB[b] = tot;
  };

  // =================== INIT1: copy small state, zero accumulators ===================
  {
    int gt = b * NTHR + tid;
    if (gt < Msz){ rw[gt] = read_w0[gt]; wwv[gt] = write_w0[gt]; }
    if (gt < 2 * Hsz) harr[gt] = 0.f;
    if (gt < Dsz) rvec[gt] = 0.f;
    if (tid < 2) s_cst[tid] = 0.f;
  }
  gbar();

  // =================== INIT2: load memory rows to LDS, norms, initial read_vec ======
  {
#pragma unroll 1
    for (int it = 0; it < 16; ++it){
      int ml = it * 4 + wv;
      int m  = b * RPB + ml;
      float4 v = *(const float4*)(mem0 + (size_t)m * Dsz + ln * 4);
      *(float4*)(&s_mem[ml * Dsz + ln * 4]) = v;
      float n2 = v.x*v.x + v.y*v.y + v.z*v.z + v.w*v.w;
      n2 = wred64(n2);
      if (ln == 0) s_norm[ml] = sqrtf(n2);
    }
    if (tid < RPB) s_a[tid] = rw[b * RPB + tid];
    __syncthreads();
    float acc = 0.f;
#pragma unroll 1
    for (int j = 0; j < RPB; ++j) acc += s_a[j] * s_mem[j * Dsz + tid];
    atomicAdd(&rvec[tid], acc);
  }
  gbar();

  // =================== time loop ===================
  for (int t = 0; t < Tlen; ++t){
    const float* hprev = harr + (t & 1) * Hsz;
    float*       hcur  = harr + ((t + 1) & 1) * Hsz;
    const float* xt    = inputs + (size_t)t * Isz;

    // ---- A: LSTM gates GEMV + elementwise (block b owns hidden units 2b, 2b+1) ----
    {
      s_co[tid] = hprev[tid]; s_co[256 + tid] = hprev[256 + tid];
      s_a[tid] = xt[tid]; s_b[tid] = rvec[tid];
      __syncthreads();
      int dd = tid >> 5;          // 0..7 : (gate 0..3) x (hidden offset 0..1)
      int l  = tid & 31;
      int jj = (b << 1) + (dd & 1);
      int g  = dd >> 1;
      int r  = g * Hsz + jj;
      const float* wi = W_ih + (size_t)r * (Isz + Dsz);
      const float* wh = W_hh + (size_t)r * Hsz;
      float acc = 0.f;
#pragma unroll
      for (int it = 0; it < 4; ++it){
        int k = it * 128 + l * 4;
        float4 a  = *(const float4*)(wi + k);
        float4 x  = (k < Isz) ? *(const float4*)(&s_a[k]) : *(const float4*)(&s_b[k - Isz]);
        acc += a.x*x.x + a.y*x.y + a.z*x.z + a.w*x.w;
        float4 hw = *(const float4*)(wh + k);
        float4 hv = *(const float4*)(&s_co[k]);
        acc += hw.x*hv.x + hw.y*hv.y + hw.z*hv.z + hw.w*hv.w;
      }
      acc = wred32(acc);
      if (l == 0) s_lg[dd] = acc + b_ih[r] + b_hh[r];
      __syncthreads();
      if (tid < 2){
        int j = (b << 1) + tid;
        float iv = s_lg[0 + tid], fv = s_lg[2 + tid], gv = s_lg[4 + tid], ov = s_lg[6 + tid];
        float cn = sigm(fv) * s_cst[tid] + sigm(iv) * tanhf(gv);
        s_cst[tid] = cn;
        hcur[j] = sigm(ov) * tanhf(cn);
      }
    }
    gbar();

    // ---- C: head projections + output GEMV (1292 dot products, 8 slots/block) ----
    {
      s_co[tid] = hcur[tid]; s_co[256 + tid] = hcur[256 + tid];
      s_c[tid]  = rvec[tid];
      __syncthreads();
#pragma unroll
      for (int q = 0; q < 2; ++q){
        int slot = b * 8 + wv * 2 + q;
        if (slot < 1292){
          const float* Wrow = nullptr; float bias = 0.f; int len = 512;
          float* dst = nullptr; bool act = false;
          if (slot < 256){ Wrow = w_Wk + (size_t)slot * Hsz; bias = w_bk[slot]; dst = keyw + slot; }
          else if (slot < 512){ int i = slot - 256; Wrow = w_We + (size_t)i * Hsz; bias = w_be[i]; dst = ersv + i; act = true; }
          else if (slot < 768){ int i = slot - 512; Wrow = w_Wa + (size_t)i * Hsz; bias = w_ba[i]; dst = addv + i; }
          else if (slot < 1024){ int i = slot - 768; Wrow = r_Wk + (size_t)i * Hsz; bias = r_bk[i]; dst = keyr + i; }
          else if (slot < 1280){ int i = slot - 1024; Wrow = Wo + (size_t)i * (Hsz + Dsz); bias = bo[i]; len = 768; dst = out + (size_t)t * Isz + i; }
          else {
            int i = slot - 1280;
            int ii = (i >= 6) ? i - 6 : i;
            bool rh = (i >= 6);
            const float *Wt, *bt; int row = 0;
            if (ii == 0){ Wt = rh ? r_Wb : w_Wb; bt = rh ? r_bb : w_bb; }
            else if (ii == 1){ Wt = rh ? r_Wg : w_Wg; bt = rh ? r_bg : w_bg; }
            else if (ii == 2){ Wt = rh ? r_Wp : w_Wp; bt = rh ? r_bp : w_bp; }
            else { Wt = rh ? r_Ws : w_Ws; bt = rh ? r_bs : w_bs; row = ii - 3; }
            Wrow = Wt + (size_t)row * Hsz; bias = bt[row]; dst = scal + i;
          }
          float acc = 0.f;
          if (len == 512){
            int k = ln * 8;
            float4 a0 = *(const float4*)(Wrow + k);
            float4 a1 = *(const float4*)(Wrow + k + 4);
            float4 c0 = *(const float4*)(&s_co[k]);
            float4 c1 = *(const float4*)(&s_co[k + 4]);
            acc = a0.x*c0.x + a0.y*c0.y + a0.z*c0.z + a0.w*c0.w
                + a1.x*c1.x + a1.y*c1.y + a1.z*c1.z + a1.w*c1.w;
          } else {
#pragma unroll 1
            for (int kk = ln; kk < 768; kk += 64){
              float x = (kk < Hsz) ? s_co[kk] : s_c[kk - Hsz];
              acc += Wrow[kk] * x;
            }
          }
          acc = wred64(acc);
          if (ln == 0){
            float v = acc + bias;
            if (act) v = sigm(v);
            *dst = v;
          }
        }
      }
    }
    gbar();

    // ---- D: write-head content scores -> e = exp(beta*(cos-1)) (shift by bound beta) ----
    {
      s_a[tid] = keyw[tid];
      float nk2 = bred256(s_a[tid] * s_a[tid]);
      float beta  = softplusf(scal[0]);
      float invbk = beta / fmaxf(sqrtf(nk2), 1e-12f);
      float esum = 0.f;
#pragma unroll 1
      for (int it = 0; it < 16; ++it){
        int ml = it * 4 + wv;
        int m  = b * RPB + ml;
        float4 v  = *(const float4*)(&s_mem[ml * Dsz + ln * 4]);
        float4 kv = *(const float4*)(&s_a[ln * 4]);
        float d = v.x*kv.x + v.y*kv.y + v.z*kv.z + v.w*kv.w;
        d = wred64(d);
        float score = d * invbk / fmaxf(s_norm[ml], 1e-12f);
        float e = __expf(score - beta);
        if (ln == 0){ buf_e[m] = e; esum += e; }
      }
      if (ln == 0) s_wsum[wv] = esum;
      __syncthreads();
      if (tid == 0) psA[b] = s_wsum[0] + s_wsum[1] + s_wsum[2] + s_wsum[3];
    }
    gbar();

    // ---- F: write-head interpolate + shift + sharpen ----
    shiftSharpen(0, wwv);
    gbar();

    // ---- H: normalize ww, memory erase/add update (LDS), new norms + read-head scores ----
    {
      s_a[tid] = ersv[tid]; s_b[tid] = addv[tid]; s_c[tid] = keyr[tid];
      float nk2 = bred256(s_c[tid] * s_c[tid]);
      float beta  = softplusf(scal[6]);
      float invbk = beta / fmaxf(sqrtf(nk2), 1e-12f);
      float Sw = bred256(psB[tid]);
      float invSw = 1.f / (Sw + 1e-8f);
      float esum = 0.f;
#pragma unroll 1
      for (int it = 0; it < 16; ++it){
        int ml = it * 4 + wv;
        int m  = b * RPB + ml;
        float wwm = s_bw[ml] * invSw;
        if (ln == 0) wwv[m] = wwm;
        int off = ml * Dsz + ln * 4;
        float4 mv = *(const float4*)(&s_mem[off]);
        float4 er = *(const float4*)(&s_a[ln * 4]);
        float4 ad = *(const float4*)(&s_b[ln * 4]);
        float4 kr = *(const float4*)(&s_c[ln * 4]);
        float4 nv;
        nv.x = mv.x * (1.f - wwm * er.x) + wwm * ad.x;
        nv.y = mv.y * (1.f - wwm * er.y) + wwm * ad.y;
        nv.z = mv.z * (1.f - wwm * er.z) + wwm * ad.z;
        nv.w = mv.w * (1.f - wwm * er.w) + wwm * ad.w;
        *(float4*)(&s_mem[off]) = nv;
        float n2 = nv.x*nv.x + nv.y*nv.y + nv.z*nv.z + nv.w*nv.w;
        float dt = nv.x*kr.x + nv.y*kr.y + nv.z*kr.z + nv.w*kr.w;
        n2 = wred64(n2);
        dt = wred64(dt);
        float nr = sqrtf(n2);
        if (ln == 0) s_norm[ml] = nr;
        float score = dt * invbk / fmaxf(nr, 1e-12f);
        float e = __expf(score - beta);
        if (ln == 0){ buf_e[m] = e; esum += e; }
      }
      if (ln == 0) s_wsum[wv] = esum;
      __syncthreads();
      if (tid == 0) psA[b] = s_wsum[0] + s_wsum[1] + s_wsum[2] + s_wsum[3];
    }
    gbar();

    // ---- J: read-head interpolate + shift + sharpen; zero read-vector accumulator ----
    shiftSharpen(6, rw);
    if (b == 0) rvec[tid] = 0.f;
    gbar();

    // ---- L: normalize rw, accumulate next read_vec = rw_new @ mem_new ----
    {
      float Sr = bred256(psB[tid]);
      float invSr = 1.f / (Sr + 1e-8f);
      if (tid < RPB){
        int m = b * RPB + tid;
        float rv = s_bw[tid] * invSr;
        rw[m] = rv;
        s_a[tid] = rv;
      }
      __syncthreads();
      float acc = 0.f;
#pragma unroll 1
      for (int j = 0; j < RPB; ++j) acc += s_a[j] * s_mem[j * Dsz + tid];
      atomicAdd(&rvec[tid], acc);
    }
    gbar();
  }
}

extern "C" void kernel_launch(void* const* d_in, const int* in_sizes, int n_in,
                              void* d_out, int out_size, void* d_ws, size_t ws_size,
                              hipStream_t stream)
{
  (void)in_sizes; (void)out_size;
  if (n_in < 34) return;
  if (ws_size < (size_t)52000 * 4) return;  // ~208KB scratch needed
  Params P;
  for (int i = 0; i < 34; ++i) P.in[i] = (const float*)d_in[i];
  P.out = (float*)d_out;
  P.ws  = (float*)d_ws;
  hipLaunchKernelGGL(ntm_kernel, dim3(NBLK), dim3(NTHR), 0, stream, P);
}

// Round 3
// 17379.057 us; speedup vs baseline: 1.2514x; 1.2514x over previous
//
#include <hip/hip_runtime.h>
#include <math.h>

// Persistent-kernel NTM, R2b: kill the buffer_wbl2 fences.
// - All cross-block stores are agent-scope relaxed atomic stores (write through
//   to LLC, bypass the per-XCD L2) -> no release fence needed at the barrier.
// - Barrier acquire side: cheap L2 invalidate only (__builtin_amdgcn_fence acquire).
// - Weight vectors (rw/ww) and content-score e-values live in LDS; only the
//   2 boundary elements per block are published globally for the shift step.
// 7 grid barriers per timestep x 128 steps.

#define NBLK 256
#define NTHR 256
#define Msz  16384
#define Dsz  256
#define Hsz  512
#define Isz  256
#define Tlen 128
#define RPB  64   // memory rows per block

struct Params {
  const float* in[34];
  float* out;
  float* ws;
};

__device__ __forceinline__ float wred64(float v){
#pragma unroll
  for (int o = 32; o > 0; o >>= 1) v += __shfl_xor(v, o, 64);
  return v;
}
__device__ __forceinline__ float wred32(float v){
#pragma unroll
  for (int o = 16; o > 0; o >>= 1) v += __shfl_xor(v, o, 32);
  return v;
}
__device__ __forceinline__ float sigm(float x){ return 1.f / (1.f + __expf(-x)); }
__device__ __forceinline__ float softplusf(float x){ return (x > 20.f) ? x : log1pf(__expf(x)); }

// agent-scope write-through store (goes to LLC, visible to all XCDs; no fence needed)
__device__ __forceinline__ void gstore(float* p, float v){
  __hip_atomic_store(p, v, __ATOMIC_RELAXED, __HIP_MEMORY_SCOPE_AGENT);
}

__global__ void __launch_bounds__(NTHR, 1)
ntm_kernel(Params P)
{
  const int b   = blockIdx.x;
  const int tid = threadIdx.x;
  const int wv  = tid >> 6;   // wave 0..3
  const int ln  = tid & 63;   // lane 0..63

  // ------- input pointers (setup_inputs dict order) -------
  const float* inputs  = P.in[0];
  const float* mem0    = P.in[1];
  const float* read_w0 = P.in[2];
  const float* write_w0= P.in[3];
  const float* W_ih = P.in[4];
  const float* W_hh = P.in[5];
  const float* b_ih = P.in[6];
  const float* b_hh = P.in[7];
  const float* Wo   = P.in[8];
  const float* bo   = P.in[9];
  const float* r_Wk = P.in[10]; const float* r_bk = P.in[11];
  const float* r_Wb = P.in[12]; const float* r_bb = P.in[13];
  const float* r_Wg = P.in[14]; const float* r_bg = P.in[15];
  const float* r_Ws = P.in[16]; const float* r_bs = P.in[17];
  const float* r_Wp = P.in[18]; const float* r_bp = P.in[19];
  const float* w_Wk = P.in[20]; const float* w_bk = P.in[21];
  const float* w_Wb = P.in[22]; const float* w_bb = P.in[23];
  const float* w_Wg = P.in[24]; const float* w_bg = P.in[25];
  const float* w_Ws = P.in[26]; const float* w_bs = P.in[27];
  const float* w_Wp = P.in[28]; const float* w_bp = P.in[29];
  const float* w_We = P.in[30]; const float* w_be = P.in[31];
  const float* w_Wa = P.in[32]; const float* w_ba = P.in[33];
  float* out = P.out;

  // ------- global scratch layout (floats) -------
  float* ws    = P.ws;
  float* harr  = ws;                 // 2*512 h double buffer
  float* keyw  = ws + 1024;          // 256
  float* keyr  = keyw + 256;         // 256
  float* ersv  = keyr + 256;         // 256 (post-sigmoid erase)
  float* addv  = ersv + 256;         // 256
  float* rvec  = addv + 256;         // 256 read vector (atomicAdd accumulator)
  float* scal  = rvec + 256;         // 16 raw head scalars
  float* psA   = scal + 16;          // 256 per-block partial e-sums
  float* psB   = psA + 256;          // 256 per-block partial sharpened-w sums
  float* eF    = psB + 256;          // 256 e[first row] per block
  float* eL    = eF + 256;           // 256 e[last row] per block
  float* pF    = eL + 256;           // 256 prev-w[first row] per block
  float* pL    = pF + 256;           // 256 prev-w[last row] per block
  unsigned int* sy = (unsigned int*)(pL + 256); // cnt, gen, flag
  unsigned int* cnt = sy;
  unsigned int* gen = sy + 1;
  unsigned int* flg = sy + 2;

  // ------- LDS -------
  __shared__ float s_mem[RPB * Dsz];   // 64KB: this block's memory rows
  __shared__ float s_co[Hsz];          // staged h/co
  __shared__ float s_a[256], s_b[256], s_c[256];
  __shared__ float s_norm[RPB];        // row norms
  __shared__ float s_e[RPB];           // content e-values (current head)
  __shared__ float s_bw[RPB];          // sharpened (unnormalized) weights
  __shared__ float s_rw[RPB];          // persistent read weights (this block's rows)
  __shared__ float s_ww[RPB];          // persistent write weights
  __shared__ float s_red[4];
  __shared__ float s_lg[8];
  __shared__ float s_wsum[4];
  __shared__ float s_cst[2];           // LSTM cell state (this block's 2 hidden units)

  // ------- sync-var init (ws is poisoned 0xAA each launch) -------
  if (b == 0 && tid == 0){
    __hip_atomic_store(cnt, 0u, __ATOMIC_RELAXED, __HIP_MEMORY_SCOPE_AGENT);
    __hip_atomic_store(gen, 0u, __ATOMIC_RELAXED, __HIP_MEMORY_SCOPE_AGENT);
    __builtin_amdgcn_s_waitcnt(0);
    __hip_atomic_store(flg, 0xC0FFEEu, __ATOMIC_RELAXED, __HIP_MEMORY_SCOPE_AGENT);
  }
  if (tid == 0){
    while (__hip_atomic_load(flg, __ATOMIC_RELAXED, __HIP_MEMORY_SCOPE_AGENT) != 0xC0FFEEu)
      __builtin_amdgcn_s_sleep(2);
  }
  __syncthreads();

  // Barrier: no release fence (all cross-block stores are write-through atomics,
  // drained by the vmcnt(0) the compiler emits for __syncthreads). Acquire side:
  // L2-invalidate only (no writeback).
  auto gbar = [&](){
    __syncthreads();
    if (tid == 0){
      unsigned int g = __hip_atomic_load(gen, __ATOMIC_RELAXED, __HIP_MEMORY_SCOPE_AGENT);
      unsigned int p = __hip_atomic_fetch_add(cnt, 1u, __ATOMIC_RELAXED, __HIP_MEMORY_SCOPE_AGENT);
      if (p == NBLK - 1u){
        __hip_atomic_store(cnt, 0u, __ATOMIC_RELAXED, __HIP_MEMORY_SCOPE_AGENT);
        __builtin_amdgcn_s_waitcnt(0);   // cnt reset lands before gen bump
        __hip_atomic_fetch_add(gen, 1u, __ATOMIC_RELAXED, __HIP_MEMORY_SCOPE_AGENT);
      } else {
        while (__hip_atomic_load(gen, __ATOMIC_RELAXED, __HIP_MEMORY_SCOPE_AGENT) == g)
          __builtin_amdgcn_s_sleep(2);
      }
    }
    __syncthreads();
    __builtin_amdgcn_fence(__ATOMIC_ACQUIRE, "agent");  // invalidate, no writeback
  };

  auto bred256 = [&](float v)->float{
    v = wred64(v);
    __syncthreads();
    if (ln == 0) s_red[wv] = v;
    __syncthreads();
    return s_red[0] + s_red[1] + s_red[2] + s_red[3];
  };

  // shift + sharpen for one head. Reads psA (per-block e-sums), s_e, s_prevw,
  // boundary arrays, scal[si..si+5]; writes s_bw and psB[b].
  auto shiftSharpen = [&](int si, float* s_prevw){
    float S = bred256(psA[tid]);
    float g     = sigm(scal[si + 1]);
    float gamma = softplusf(scal[si + 2]) + 1.f;
    float a0 = scal[si + 3], a1 = scal[si + 4], a2 = scal[si + 5];
    float mx = fmaxf(a0, fmaxf(a1, a2));
    float e0 = __expf(a0 - mx), e1 = __expf(a1 - mx), e2 = __expf(a2 - mx);
    float idn = 1.f / (e0 + e1 + e2);
    float s0 = e0 * idn, s1 = e1 * idn, s2 = e2 * idn;
    float invS = 1.f / S;
    float w = 0.f;
    if (tid < RPB){
      float gc = g * invS, gp = 1.f - g;
      float em = s_e[tid],  pm = s_prevw[tid];
      float e1n = (tid < RPB-1) ? s_e[tid+1]     : eF[(b + 1) & (NBLK-1)];
      float p1n = (tid < RPB-1) ? s_prevw[tid+1] : pF[(b + 1) & (NBLK-1)];
      float e2n = (tid > 0)     ? s_e[tid-1]     : eL[(b - 1) & (NBLK-1)];
      float p2n = (tid > 0)     ? s_prevw[tid-1] : pL[(b - 1) & (NBLK-1)];
      float gwm = gc * em  + gp * pm;
      float gw1 = gc * e1n + gp * p1n;   // roll(gw,-1)[m] = gw[m+1]
      float gw2 = gc * e2n + gp * p2n;   // roll(gw,+1)[m] = gw[m-1]
      float sh = s0 * gw1 + s1 * gwm + s2 * gw2;
      w = powf(sh, gamma);
      s_bw[tid] = w;
    }
    float tot = wred64(w);               // wave0 holds all 64 row values
    if (tid == 0) gstore(&psB[b], tot);
  };

  // =================== INIT1: zero shared state, load persistent weights ===========
  {
    if (b == 0){
#pragma unroll
      for (int k = 0; k < 4; ++k) gstore(&harr[k * 256 + tid], 0.f);
    }
    if (b == 1) gstore(&rvec[tid], 0.f);
    if (tid < RPB){
      s_rw[tid] = read_w0[b * RPB + tid];
      s_ww[tid] = write_w0[b * RPB + tid];
    }
    if (tid < 2) s_cst[tid] = 0.f;
  }
  gbar();

  // =================== INIT2: memory rows -> LDS, norms, initial read_vec ==========
  {
#pragma unroll 1
    for (int it = 0; it < 16; ++it){
      int ml = it * 4 + wv;
      int m  = b * RPB + ml;
      float4 v = *(const float4*)(mem0 + (size_t)m * Dsz + ln * 4);
      *(float4*)(&s_mem[ml * Dsz + ln * 4]) = v;
      float n2 = v.x*v.x + v.y*v.y + v.z*v.z + v.w*v.w;
      n2 = wred64(n2);
      if (ln == 0) s_norm[ml] = sqrtf(n2);
    }
    __syncthreads();
    float acc = 0.f;
#pragma unroll 1
    for (int j = 0; j < RPB; ++j) acc += s_rw[j] * s_mem[j * Dsz + tid];
    atomicAdd(&rvec[tid], acc);
  }
  gbar();

  // =================== time loop ===================
  for (int t = 0; t < Tlen; ++t){
    const float* hprev = harr + (t & 1) * Hsz;
    float*       hcur  = harr + ((t + 1) & 1) * Hsz;
    const float* xt    = inputs + (size_t)t * Isz;

    // ---- A: LSTM gates GEMV + elementwise (block b owns hidden units 2b, 2b+1) ----
    {
      s_co[tid] = hprev[tid]; s_co[256 + tid] = hprev[256 + tid];
      s_a[tid] = xt[tid]; s_b[tid] = rvec[tid];
      __syncthreads();
      int dd = tid >> 5;          // 0..7 : (gate 0..3) x (hidden offset 0..1)
      int l  = tid & 31;
      int jj = (b << 1) + (dd & 1);
      int g  = dd >> 1;
      int r  = g * Hsz + jj;
      const float* wi = W_ih + (size_t)r * (Isz + Dsz);
      const float* wh = W_hh + (size_t)r * Hsz;
      float acc = 0.f;
#pragma unroll
      for (int it = 0; it < 4; ++it){
        int k = it * 128 + l * 4;
        float4 a  = *(const float4*)(wi + k);
        float4 x  = (k < Isz) ? *(const float4*)(&s_a[k]) : *(const float4*)(&s_b[k - Isz]);
        acc += a.x*x.x + a.y*x.y + a.z*x.z + a.w*x.w;
        float4 hw = *(const float4*)(wh + k);
        float4 hv = *(const float4*)(&s_co[k]);
        acc += hw.x*hv.x + hw.y*hv.y + hw.z*hv.z + hw.w*hv.w;
      }
      acc = wred32(acc);
      if (l == 0) s_lg[dd] = acc + b_ih[r] + b_hh[r];
      __syncthreads();
      if (tid < 2){
        int j = (b << 1) + tid;
        float iv = s_lg[0 + tid], fv = s_lg[2 + tid], gv = s_lg[4 + tid], ov = s_lg[6 + tid];
        float cn = sigm(fv) * s_cst[tid] + sigm(iv) * tanhf(gv);
        s_cst[tid] = cn;
        gstore(&hcur[j], sigm(ov) * tanhf(cn));
      }
    }
    gbar();

    // ---- C: head projections + output GEMV (1292 dot products, 8 slots/block) ----
    {
      s_co[tid] = hcur[tid]; s_co[256 + tid] = hcur[256 + tid];
      s_c[tid]  = rvec[tid];
      __syncthreads();
#pragma unroll
      for (int q = 0; q < 2; ++q){
        int slot = b * 8 + wv * 2 + q;
        if (slot < 1292){
          const float* Wrow = nullptr; float bias = 0.f; int len = 512;
          float* dst = nullptr; bool act = false; bool plain = false;
          if (slot < 256){ Wrow = w_Wk + (size_t)slot * Hsz; bias = w_bk[slot]; dst = keyw + slot; }
          else if (slot < 512){ int i = slot - 256; Wrow = w_We + (size_t)i * Hsz; bias = w_be[i]; dst = ersv + i; act = true; }
          else if (slot < 768){ int i = slot - 512; Wrow = w_Wa + (size_t)i * Hsz; bias = w_ba[i]; dst = addv + i; }
          else if (slot < 1024){ int i = slot - 768; Wrow = r_Wk + (size_t)i * Hsz; bias = r_bk[i]; dst = keyr + i; }
          else if (slot < 1280){ int i = slot - 1024; Wrow = Wo + (size_t)i * (Hsz + Dsz); bias = bo[i]; len = 768; dst = out + (size_t)t * Isz + i; plain = true; }
          else {
            int i = slot - 1280;
            int ii = (i >= 6) ? i - 6 : i;
            bool rh = (i >= 6);
            const float *Wt, *bt; int row = 0;
            if (ii == 0){ Wt = rh ? r_Wb : w_Wb; bt = rh ? r_bb : w_bb; }
            else if (ii == 1){ Wt = rh ? r_Wg : w_Wg; bt = rh ? r_bg : w_bg; }
            else if (ii == 2){ Wt = rh ? r_Wp : w_Wp; bt = rh ? r_bp : w_bp; }
            else { Wt = rh ? r_Ws : w_Ws; bt = rh ? r_bs : w_bs; row = ii - 3; }
            Wrow = Wt + (size_t)row * Hsz; bias = bt[row]; dst = scal + i;
          }
          float acc = 0.f;
          if (len == 512){
            int k = ln * 8;
            float4 a0 = *(const float4*)(Wrow + k);
            float4 a1 = *(const float4*)(Wrow + k + 4);
            float4 c0 = *(const float4*)(&s_co[k]);
            float4 c1 = *(const float4*)(&s_co[k + 4]);
            acc = a0.x*c0.x + a0.y*c0.y + a0.z*c0.z + a0.w*c0.w
                + a1.x*c1.x + a1.y*c1.y + a1.z*c1.z + a1.w*c1.w;
          } else {
#pragma unroll 1
            for (int kk = ln; kk < 768; kk += 64){
              float x = (kk < Hsz) ? s_co[kk] : s_c[kk - Hsz];
              acc += Wrow[kk] * x;
            }
          }
          acc = wred64(acc);
          if (ln == 0){
            float v = acc + bias;
            if (act) v = sigm(v);
            if (plain) *dst = v; else gstore(dst, v);
          }
        }
      }
    }
    gbar();

    // ---- D: write-head content scores -> s_e = exp(beta*(cos-1)); publish sums+bounds ----
    {
      s_a[tid] = keyw[tid];
      float nk2 = bred256(s_a[tid] * s_a[tid]);
      float beta  = softplusf(scal[0]);
      float invbk = beta / fmaxf(sqrtf(nk2), 1e-12f);
      float esum = 0.f;
#pragma unroll 1
      for (int it = 0; it < 16; ++it){
        int ml = it * 4 + wv;
        float4 v  = *(const float4*)(&s_mem[ml * Dsz + ln * 4]);
        float4 kv = *(const float4*)(&s_a[ln * 4]);
        float d = v.x*kv.x + v.y*kv.y + v.z*kv.z + v.w*kv.w;
        d = wred64(d);
        float score = d * invbk / fmaxf(s_norm[ml], 1e-12f);
        float e = __expf(score - beta);
        if (ln == 0){ s_e[ml] = e; esum += e; }
      }
      if (ln == 0) s_wsum[wv] = esum;
      __syncthreads();
      if (tid == 0){
        gstore(&psA[b], s_wsum[0] + s_wsum[1] + s_wsum[2] + s_wsum[3]);
        gstore(&eF[b], s_e[0]);  gstore(&eL[b], s_e[RPB-1]);
        gstore(&pF[b], s_ww[0]); gstore(&pL[b], s_ww[RPB-1]);
      }
    }
    gbar();

    // ---- F: write-head interpolate + shift + sharpen ----
    shiftSharpen(0, s_ww);
    gbar();

    // ---- H: normalize ww, memory erase/add update (LDS), new norms + read-head scores ----
    {
      s_a[tid] = ersv[tid]; s_b[tid] = addv[tid]; s_c[tid] = keyr[tid];
      float nk2 = bred256(s_c[tid] * s_c[tid]);
      float beta  = softplusf(scal[6]);
      float invbk = beta / fmaxf(sqrtf(nk2), 1e-12f);
      float Sw = bred256(psB[tid]);
      float invSw = 1.f / (Sw + 1e-8f);
      if (tid < RPB) s_ww[tid] = s_bw[tid] * invSw;   // persist normalized write weights
      float esum = 0.f;
#pragma unroll 1
      for (int it = 0; it < 16; ++it){
        int ml = it * 4 + wv;
        float wwm = s_bw[ml] * invSw;
        int off = ml * Dsz + ln * 4;
        float4 mv = *(const float4*)(&s_mem[off]);
        float4 er = *(const float4*)(&s_a[ln * 4]);
        float4 ad = *(const float4*)(&s_b[ln * 4]);
        float4 kr = *(const float4*)(&s_c[ln * 4]);
        float4 nv;
        nv.x = mv.x * (1.f - wwm * er.x) + wwm * ad.x;
        nv.y = mv.y * (1.f - wwm * er.y) + wwm * ad.y;
        nv.z = mv.z * (1.f - wwm * er.z) + wwm * ad.z;
        nv.w = mv.w * (1.f - wwm * er.w) + wwm * ad.w;
        *(float4*)(&s_mem[off]) = nv;
        float n2 = nv.x*nv.x + nv.y*nv.y + nv.z*nv.z + nv.w*nv.w;
        float dt = nv.x*kr.x + nv.y*kr.y + nv.z*kr.z + nv.w*kr.w;
        n2 = wred64(n2);
        dt = wred64(dt);
        float nr = sqrtf(n2);
        if (ln == 0) s_norm[ml] = nr;
        float score = dt * invbk / fmaxf(nr, 1e-12f);
        float e = __expf(score - beta);
        if (ln == 0){ s_e[ml] = e; esum += e; }
      }
      if (ln == 0) s_wsum[wv] = esum;
      __syncthreads();
      if (tid == 0){
        gstore(&psA[b], s_wsum[0] + s_wsum[1] + s_wsum[2] + s_wsum[3]);
        gstore(&eF[b], s_e[0]);  gstore(&eL[b], s_e[RPB-1]);
        gstore(&pF[b], s_rw[0]); gstore(&pL[b], s_rw[RPB-1]);
      }
    }
    gbar();

    // ---- J: read-head interpolate + shift + sharpen; zero read-vector accumulator ----
    shiftSharpen(6, s_rw);
    if (b == 0) gstore(&rvec[tid], 0.f);
    gbar();

    // ---- L: normalize rw, accumulate next read_vec = rw_new @ mem_new ----
    {
      float Sr = bred256(psB[tid]);
      float invSr = 1.f / (Sr + 1e-8f);
      if (tid < RPB) s_rw[tid] = s_bw[tid] * invSr;
      __syncthreads();
      float acc = 0.f;
#pragma unroll 1
      for (int j = 0; j < RPB; ++j) acc += s_rw[j] * s_mem[j * Dsz + tid];
      atomicAdd(&rvec[tid], acc);
    }
    gbar();
  }
}

extern "C" void kernel_launch(void* const* d_in, const int* in_sizes, int n_in,
                              void* d_out, int out_size, void* d_ws, size_t ws_size,
                              hipStream_t stream)
{
  (void)in_sizes; (void)out_size;
  if (n_in < 34) return;
  if (ws_size < (size_t)16384) return;   // ~16KB scratch needed
  Params P;
  for (int i = 0; i < 34; ++i) P.in[i] = (const float*)d_in[i];
  P.out = (float*)d_out;
  P.ws  = (float*)d_ws;
  hipLaunchKernelGGL(ntm_kernel, dim3(NBLK), dim3(NTHR), 0, stream, P);
}

// Round 4
// 13628.964 us; speedup vs baseline: 1.5958x; 1.2752x over previous
//
#include <hip/hip_runtime.h>
#include <math.h>

// Persistent-kernel NTM, R4: zero-RMW flag barrier + split rvec atomics.
// - Barrier: block leader stores epoch to flags[b]; wave 0 of every block polls
//   all 256 flags (4 per lane) until >= epoch. No central counter RMW convoy.
// - rvec reduction split into 8 contention groups (rvec_parts[8][256]).
// - All cross-block stores remain agent-scope relaxed atomics (LLC write-through);
//   acquire-only fence (L2 invalidate, no writeback) after each barrier.
// 7 grid barriers per timestep x 128 steps.

#define NBLK 256
#define NTHR 256
#define Msz  16384
#define Dsz  256
#define Hsz  512
#define Isz  256
#define Tlen 128
#define RPB  64   // memory rows per block

struct Params {
  const float* in[34];
  float* out;
  float* ws;
};

__device__ __forceinline__ float wred64(float v){
#pragma unroll
  for (int o = 32; o > 0; o >>= 1) v += __shfl_xor(v, o, 64);
  return v;
}
__device__ __forceinline__ float wred32(float v){
#pragma unroll
  for (int o = 16; o > 0; o >>= 1) v += __shfl_xor(v, o, 32);
  return v;
}
__device__ __forceinline__ float sigm(float x){ return 1.f / (1.f + __expf(-x)); }
__device__ __forceinline__ float softplusf(float x){ return (x > 20.f) ? x : log1pf(__expf(x)); }

// agent-scope write-through store/load (LLC-direct, visible across XCDs)
__device__ __forceinline__ void gstore(float* p, float v){
  __hip_atomic_store(p, v, __ATOMIC_RELAXED, __HIP_MEMORY_SCOPE_AGENT);
}
__device__ __forceinline__ void gstoreu(unsigned int* p, unsigned int v){
  __hip_atomic_store(p, v, __ATOMIC_RELAXED, __HIP_MEMORY_SCOPE_AGENT);
}
__device__ __forceinline__ unsigned int gloadu(const unsigned int* p){
  return __hip_atomic_load(p, __ATOMIC_RELAXED, __HIP_MEMORY_SCOPE_AGENT);
}

__global__ void __launch_bounds__(NTHR, 1)
ntm_kernel(Params P)
{
  const int b   = blockIdx.x;
  const int tid = threadIdx.x;
  const int wv  = tid >> 6;   // wave 0..3
  const int ln  = tid & 63;   // lane 0..63

  // ------- input pointers (setup_inputs dict order) -------
  const float* inputs  = P.in[0];
  const float* mem0    = P.in[1];
  const float* read_w0 = P.in[2];
  const float* write_w0= P.in[3];
  const float* W_ih = P.in[4];
  const float* W_hh = P.in[5];
  const float* b_ih = P.in[6];
  const float* b_hh = P.in[7];
  const float* Wo   = P.in[8];
  const float* bo   = P.in[9];
  const float* r_Wk = P.in[10]; const float* r_bk = P.in[11];
  const float* r_Wb = P.in[12]; const float* r_bb = P.in[13];
  const float* r_Wg = P.in[14]; const float* r_bg = P.in[15];
  const float* r_Ws = P.in[16]; const float* r_bs = P.in[17];
  const float* r_Wp = P.in[18]; const float* r_bp = P.in[19];
  const float* w_Wk = P.in[20]; const float* w_bk = P.in[21];
  const float* w_Wb = P.in[22]; const float* w_bb = P.in[23];
  const float* w_Wg = P.in[24]; const float* w_bg = P.in[25];
  const float* w_Ws = P.in[26]; const float* w_bs = P.in[27];
  const float* w_Wp = P.in[28]; const float* w_bp = P.in[29];
  const float* w_We = P.in[30]; const float* w_be = P.in[31];
  const float* w_Wa = P.in[32]; const float* w_ba = P.in[33];
  float* out = P.out;

  // ------- global scratch layout (floats) -------
  float* ws    = P.ws;
  float* harr  = ws;                 // 2*512 h double buffer
  float* keyw  = ws + 1024;          // 256
  float* keyr  = keyw + 256;         // 256
  float* ersv  = keyr + 256;         // 256 (post-sigmoid erase)
  float* addv  = ersv + 256;         // 256
  float* scal  = addv + 256;         // 16 raw head scalars
  float* psA   = scal + 16;          // 256 per-block partial e-sums
  float* psB   = psA + 256;          // 256 per-block partial sharpened-w sums
  float* eF    = psB + 256;          // 256 e[first row] per block
  float* eL    = eF + 256;           // 256 e[last row] per block
  float* pF    = eL + 256;           // 256 prev-w[first row] per block
  float* pL    = pF + 256;           // 256 prev-w[last row] per block
  float* parts = pL + 256;           // 8*256 rvec partial accumulators
  unsigned int* flags = (unsigned int*)(parts + 8*256); // 256 barrier flags
  unsigned int* flg   = flags + 256;                    // init sentinel

  // ------- LDS -------
  __shared__ float s_mem[RPB * Dsz];   // 64KB: this block's memory rows
  __shared__ float s_co[Hsz];          // staged h/co
  __shared__ float s_a[256], s_b[256], s_c[256];
  __shared__ float s_rv[256];          // current read vector
  __shared__ float s_norm[RPB];        // row norms
  __shared__ float s_e[RPB];           // content e-values (current head)
  __shared__ float s_bw[RPB];          // sharpened (unnormalized) weights
  __shared__ float s_rw[RPB];          // persistent read weights (this block's rows)
  __shared__ float s_ww[RPB];          // persistent write weights
  __shared__ float s_red[4];
  __shared__ float s_lg[8];
  __shared__ float s_wsum[4];
  __shared__ float s_cst[2];           // LSTM cell state (this block's 2 hidden units)

  unsigned int ep = 1;                 // barrier epoch

  // ------- INIT1 + handshake (ws is poisoned 0xAA each launch) -------
  {
    if (b == 0){
      gstoreu(&flags[tid], 0u);
#pragma unroll
      for (int k = 0; k < 4; ++k) gstore(&harr[k * 256 + tid], 0.f);
    }
    if (b < 8) gstore(&parts[b * 256 + tid], 0.f);   // zero rvec parts
    if (tid < RPB){
      s_rw[tid] = read_w0[b * RPB + tid];
      s_ww[tid] = write_w0[b * RPB + tid];
    }
    if (tid < 2) s_cst[tid] = 0.f;
    __syncthreads();                     // drains each wave's stores (vmcnt 0)
    if (b == 0 && tid == 0) gstoreu(flg, 0xC0FFEEu);
    if (tid == 0){
      while (gloadu(flg) != 0xC0FFEEu) __builtin_amdgcn_s_sleep(2);
    }
    __syncthreads();
    __builtin_amdgcn_fence(__ATOMIC_ACQUIRE, "agent");
  }

  // Flag barrier: leader publishes epoch; wave 0 polls all 256 flags.
  auto gbar = [&](){
    __syncthreads();                     // all waves' phase stores drained
    if (tid == 0) gstoreu(&flags[b], ep);
    if (wv == 0){
      for (;;){
        unsigned int a0 = gloadu(&flags[ln]);
        unsigned int a1 = gloadu(&flags[64 + ln]);
        unsigned int a2 = gloadu(&flags[128 + ln]);
        unsigned int a3 = gloadu(&flags[192 + ln]);
        bool ok = ((int)(a0 - ep) >= 0) && ((int)(a1 - ep) >= 0)
               && ((int)(a2 - ep) >= 0) && ((int)(a3 - ep) >= 0);
        if (__all(ok)) break;
        __builtin_amdgcn_s_sleep(1);
      }
    }
    __syncthreads();
    __builtin_amdgcn_fence(__ATOMIC_ACQUIRE, "agent");  // invalidate, no writeback
    ++ep;
  };

  auto bred256 = [&](float v)->float{
    v = wred64(v);
    __syncthreads();
    if (ln == 0) s_red[wv] = v;
    __syncthreads();
    return s_red[0] + s_red[1] + s_red[2] + s_red[3];
  };

  // shift + sharpen for one head. Reads psA (per-block e-sums), s_e, s_prevw,
  // boundary arrays, scal[si..si+5]; writes s_bw and psB[b].
  auto shiftSharpen = [&](int si, float* s_prevw){
    float S = bred256(psA[tid]);
    float g     = sigm(scal[si + 1]);
    float gamma = softplusf(scal[si + 2]) + 1.f;
    float a0 = scal[si + 3], a1 = scal[si + 4], a2 = scal[si + 5];
    float mx = fmaxf(a0, fmaxf(a1, a2));
    float e0 = __expf(a0 - mx), e1 = __expf(a1 - mx), e2 = __expf(a2 - mx);
    float idn = 1.f / (e0 + e1 + e2);
    float s0 = e0 * idn, s1 = e1 * idn, s2 = e2 * idn;
    float invS = 1.f / S;
    float w = 0.f;
    if (tid < RPB){
      float gc = g * invS, gp = 1.f - g;
      float em = s_e[tid],  pm = s_prevw[tid];
      float e1n = (tid < RPB-1) ? s_e[tid+1]     : eF[(b + 1) & (NBLK-1)];
      float p1n = (tid < RPB-1) ? s_prevw[tid+1] : pF[(b + 1) & (NBLK-1)];
      float e2n = (tid > 0)     ? s_e[tid-1]     : eL[(b - 1) & (NBLK-1)];
      float p2n = (tid > 0)     ? s_prevw[tid-1] : pL[(b - 1) & (NBLK-1)];
      float gwm = gc * em  + gp * pm;
      float gw1 = gc * e1n + gp * p1n;   // roll(gw,-1)[m] = gw[m+1]
      float gw2 = gc * e2n + gp * p2n;   // roll(gw,+1)[m] = gw[m-1]
      float sh = s0 * gw1 + s1 * gwm + s2 * gw2;
      w = powf(sh, gamma);
      s_bw[tid] = w;
    }
    float tot = wred64(w);               // wave0 holds all 64 row values
    if (tid == 0) gstore(&psB[b], tot);
  };

  // =================== INIT2: memory rows -> LDS, norms, initial read_vec ==========
  {
#pragma unroll 1
    for (int it = 0; it < 16; ++it){
      int ml = it * 4 + wv;
      int m  = b * RPB + ml;
      float4 v = *(const float4*)(mem0 + (size_t)m * Dsz + ln * 4);
      *(float4*)(&s_mem[ml * Dsz + ln * 4]) = v;
      float n2 = v.x*v.x + v.y*v.y + v.z*v.z + v.w*v.w;
      n2 = wred64(n2);
      if (ln == 0) s_norm[ml] = sqrtf(n2);
    }
    __syncthreads();
    float acc = 0.f;
#pragma unroll 1
    for (int j = 0; j < RPB; ++j) acc += s_rw[j] * s_mem[j * Dsz + tid];
    atomicAdd(&parts[(b & 7) * 256 + tid], acc);
  }
  gbar();

  // =================== time loop ===================
  for (int t = 0; t < Tlen; ++t){
    const float* hprev = harr + (t & 1) * Hsz;
    float*       hcur  = harr + ((t + 1) & 1) * Hsz;
    const float* xt    = inputs + (size_t)t * Isz;

    // ---- A: sum rvec parts; LSTM gates GEMV + elementwise (block owns h 2b,2b+1) ----
    {
      s_co[tid] = hprev[tid]; s_co[256 + tid] = hprev[256 + tid];
      s_a[tid] = xt[tid];
      float rv = 0.f;
#pragma unroll
      for (int p = 0; p < 8; ++p) rv += parts[p * 256 + tid];
      s_rv[tid] = rv;
      __syncthreads();
      int dd = tid >> 5;          // 0..7 : (gate 0..3) x (hidden offset 0..1)
      int l  = tid & 31;
      int jj = (b << 1) + (dd & 1);
      int g  = dd >> 1;
      int r  = g * Hsz + jj;
      const float* wi = W_ih + (size_t)r * (Isz + Dsz);
      const float* wh = W_hh + (size_t)r * Hsz;
      float acc = 0.f;
#pragma unroll
      for (int it = 0; it < 4; ++it){
        int k = it * 128 + l * 4;
        float4 a  = *(const float4*)(wi + k);
        float4 x  = (k < Isz) ? *(const float4*)(&s_a[k]) : *(const float4*)(&s_rv[k - Isz]);
        acc += a.x*x.x + a.y*x.y + a.z*x.z + a.w*x.w;
        float4 hw = *(const float4*)(wh + k);
        float4 hv = *(const float4*)(&s_co[k]);
        acc += hw.x*hv.x + hw.y*hv.y + hw.z*hv.z + hw.w*hv.w;
      }
      acc = wred32(acc);
      if (l == 0) s_lg[dd] = acc + b_ih[r] + b_hh[r];
      __syncthreads();
      if (tid < 2){
        int j = (b << 1) + tid;
        float iv = s_lg[0 + tid], fv = s_lg[2 + tid], gv = s_lg[4 + tid], ov = s_lg[6 + tid];
        float cn = sigm(fv) * s_cst[tid] + sigm(iv) * tanhf(gv);
        s_cst[tid] = cn;
        gstore(&hcur[j], sigm(ov) * tanhf(cn));
      }
    }
    gbar();

    // ---- C: head projections + output GEMV (1292 dot products, 8 slots/block) ----
    {
      s_co[tid] = hcur[tid]; s_co[256 + tid] = hcur[256 + tid];
      __syncthreads();
#pragma unroll
      for (int q = 0; q < 2; ++q){
        int slot = b * 8 + wv * 2 + q;
        if (slot < 1292){
          const float* Wrow = nullptr; float bias = 0.f; int len = 512;
          float* dst = nullptr; bool act = false; bool plain = false;
          if (slot < 256){ Wrow = w_Wk + (size_t)slot * Hsz; bias = w_bk[slot]; dst = keyw + slot; }
          else if (slot < 512){ int i = slot - 256; Wrow = w_We + (size_t)i * Hsz; bias = w_be[i]; dst = ersv + i; act = true; }
          else if (slot < 768){ int i = slot - 512; Wrow = w_Wa + (size_t)i * Hsz; bias = w_ba[i]; dst = addv + i; }
          else if (slot < 1024){ int i = slot - 768; Wrow = r_Wk + (size_t)i * Hsz; bias = r_bk[i]; dst = keyr + i; }
          else if (slot < 1280){ int i = slot - 1024; Wrow = Wo + (size_t)i * (Hsz + Dsz); bias = bo[i]; len = 768; dst = out + (size_t)t * Isz + i; plain = true; }
          else {
            int i = slot - 1280;
            int ii = (i >= 6) ? i - 6 : i;
            bool rh = (i >= 6);
            const float *Wt, *bt; int row = 0;
            if (ii == 0){ Wt = rh ? r_Wb : w_Wb; bt = rh ? r_bb : w_bb; }
            else if (ii == 1){ Wt = rh ? r_Wg : w_Wg; bt = rh ? r_bg : w_bg; }
            else if (ii == 2){ Wt = rh ? r_Wp : w_Wp; bt = rh ? r_bp : w_bp; }
            else { Wt = rh ? r_Ws : w_Ws; bt = rh ? r_bs : w_bs; row = ii - 3; }
            Wrow = Wt + (size_t)row * Hsz; bias = bt[row]; dst = scal + i;
          }
          float acc = 0.f;
          if (len == 512){
            int k = ln * 8;
            float4 a0 = *(const float4*)(Wrow + k);
            float4 a1 = *(const float4*)(Wrow + k + 4);
            float4 c0 = *(const float4*)(&s_co[k]);
            float4 c1 = *(const float4*)(&s_co[k + 4]);
            acc = a0.x*c0.x + a0.y*c0.y + a0.z*c0.z + a0.w*c0.w
                + a1.x*c1.x + a1.y*c1.y + a1.z*c1.z + a1.w*c1.w;
          } else {
#pragma unroll 1
            for (int kk = ln; kk < 768; kk += 64){
              float x = (kk < Hsz) ? s_co[kk] : s_rv[kk - Hsz];
              acc += Wrow[kk] * x;
            }
          }
          acc = wred64(acc);
          if (ln == 0){
            float v = acc + bias;
            if (act) v = sigm(v);
            if (plain) *dst = v; else gstore(dst, v);
          }
        }
      }
    }
    gbar();

    // ---- D: write-head content scores -> s_e = exp(beta*(cos-1)); publish sums+bounds ----
    {
      s_a[tid] = keyw[tid];
      float nk2 = bred256(s_a[tid] * s_a[tid]);
      float beta  = softplusf(scal[0]);
      float invbk = beta / fmaxf(sqrtf(nk2), 1e-12f);
      float esum = 0.f;
#pragma unroll 1
      for (int it = 0; it < 16; ++it){
        int ml = it * 4 + wv;
        float4 v  = *(const float4*)(&s_mem[ml * Dsz + ln * 4]);
        float4 kv = *(const float4*)(&s_a[ln * 4]);
        float d = v.x*kv.x + v.y*kv.y + v.z*kv.z + v.w*kv.w;
        d = wred64(d);
        float score = d * invbk / fmaxf(s_norm[ml], 1e-12f);
        float e = __expf(score - beta);
        if (ln == 0){ s_e[ml] = e; esum += e; }
      }
      if (ln == 0) s_wsum[wv] = esum;
      __syncthreads();
      if (tid == 0){
        gstore(&psA[b], s_wsum[0] + s_wsum[1] + s_wsum[2] + s_wsum[3]);
        gstore(&eF[b], s_e[0]);  gstore(&eL[b], s_e[RPB-1]);
        gstore(&pF[b], s_ww[0]); gstore(&pL[b], s_ww[RPB-1]);
      }
    }
    gbar();

    // ---- F: write-head interpolate + shift + sharpen; zero rvec parts for this step ----
    shiftSharpen(0, s_ww);
    if (b < 8) gstore(&parts[b * 256 + tid], 0.f);
    gbar();

    // ---- H: normalize ww, memory erase/add update (LDS), new norms + read-head scores ----
    {
      s_a[tid] = ersv[tid]; s_b[tid] = addv[tid]; s_c[tid] = keyr[tid];
      float nk2 = bred256(s_c[tid] * s_c[tid]);
      float beta  = softplusf(scal[6]);
      float invbk = beta / fmaxf(sqrtf(nk2), 1e-12f);
      float Sw = bred256(psB[tid]);
      float invSw = 1.f / (Sw + 1e-8f);
      if (tid < RPB) s_ww[tid] = s_bw[tid] * invSw;   // persist normalized write weights
      float esum = 0.f;
#pragma unroll 1
      for (int it = 0; it < 16; ++it){
        int ml = it * 4 + wv;
        float wwm = s_bw[ml] * invSw;
        int off = ml * Dsz + ln * 4;
        float4 mv = *(const float4*)(&s_mem[off]);
        float4 er = *(const float4*)(&s_a[ln * 4]);
        float4 ad = *(const float4*)(&s_b[ln * 4]);
        float4 kr = *(const float4*)(&s_c[ln * 4]);
        float4 nv;
        nv.x = mv.x * (1.f - wwm * er.x) + wwm * ad.x;
        nv.y = mv.y * (1.f - wwm * er.y) + wwm * ad.y;
        nv.z = mv.z * (1.f - wwm * er.z) + wwm * ad.z;
        nv.w = mv.w * (1.f - wwm * er.w) + wwm * ad.w;
        *(float4*)(&s_mem[off]) = nv;
        float n2 = nv.x*nv.x + nv.y*nv.y + nv.z*nv.z + nv.w*nv.w;
        float dt = nv.x*kr.x + nv.y*kr.y + nv.z*kr.z + nv.w*kr.w;
        n2 = wred64(n2);
        dt = wred64(dt);
        float nr = sqrtf(n2);
        if (ln == 0) s_norm[ml] = nr;
        float score = dt * invbk / fmaxf(nr, 1e-12f);
        float e = __expf(score - beta);
        if (ln == 0){ s_e[ml] = e; esum += e; }
      }
      if (ln == 0) s_wsum[wv] = esum;
      __syncthreads();
      if (tid == 0){
        gstore(&psA[b], s_wsum[0] + s_wsum[1] + s_wsum[2] + s_wsum[3]);
        gstore(&eF[b], s_e[0]);  gstore(&eL[b], s_e[RPB-1]);
        gstore(&pF[b], s_rw[0]); gstore(&pL[b], s_rw[RPB-1]);
      }
    }
    gbar();

    // ---- J: read-head interpolate + shift + sharpen ----
    shiftSharpen(6, s_rw);
    gbar();

    // ---- L: normalize rw, accumulate next read_vec = rw_new @ mem_new ----
    {
      float Sr = bred256(psB[tid]);
      float invSr = 1.f / (Sr + 1e-8f);
      if (tid < RPB) s_rw[tid] = s_bw[tid] * invSr;
      __syncthreads();
      float acc = 0.f;
#pragma unroll 1
      for (int j = 0; j < RPB; ++j) acc += s_rw[j] * s_mem[j * Dsz + tid];
      atomicAdd(&parts[(b & 7) * 256 + tid], acc);
    }
    gbar();
  }
}

extern "C" void kernel_launch(void* const* d_in, const int* in_sizes, int n_in,
                              void* d_out, int out_size, void* d_ws, size_t ws_size,
                              hipStream_t stream)
{
  (void)in_sizes; (void)out_size;
  if (n_in < 34) return;
  if (ws_size < (size_t)65536) return;   // ~32KB scratch needed; require 64KB
  Params P;
  for (int i = 0; i < 34; ++i) P.in[i] = (const float*)d_in[i];
  P.out = (float*)d_out;
  P.ws  = (float*)d_ws;
  hipLaunchKernelGGL(ntm_kernel, dim3(NBLK), dim3(NTHR), 0, stream, P);
}

// Round 5
// 12476.304 us; speedup vs baseline: 1.7432x; 1.0924x over previous
//
#include <hip/hip_runtime.h>
#include <math.h>

// Persistent-kernel NTM, R5: master/worker barrier (no poll storm).
// - Arrival: each block's leader stores epoch to its OWN cacheline-padded flag.
// - Block 0 wave 0 polls the 256 flags (only poller of those lines), then
//   publishes a single `go` epoch; other blocks poll `go` with ONE lane each.
// - sc1 (L2-bypass) accesses only for sync vars + tiny cross-block scalars;
//   bulk hot data read via plain loads (L2-coalesced per XCD after inv).
// - rvec reduction split into 32 contention groups.
// 7 grid barriers per timestep x 128 steps.

#define NBLK 256
#define NTHR 256
#define Msz  16384
#define Dsz  256
#define Hsz  512
#define Isz  256
#define Tlen 128
#define RPB  64    // memory rows per block
#define NG   32    // rvec atomic groups
#define FSTR 32    // flag stride in uints (128B line)

struct Params {
  const float* in[34];
  float* out;
  float* ws;
};

__device__ __forceinline__ float wred64(float v){
#pragma unroll
  for (int o = 32; o > 0; o >>= 1) v += __shfl_xor(v, o, 64);
  return v;
}
__device__ __forceinline__ float wred32(float v){
#pragma unroll
  for (int o = 16; o > 0; o >>= 1) v += __shfl_xor(v, o, 32);
  return v;
}
__device__ __forceinline__ float sigm(float x){ return 1.f / (1.f + __expf(-x)); }
__device__ __forceinline__ float softplusf(float x){ return (x > 20.f) ? x : log1pf(__expf(x)); }

// agent-scope write-through store/load (LLC-direct, visible across XCDs)
__device__ __forceinline__ void gstore(float* p, float v){
  __hip_atomic_store(p, v, __ATOMIC_RELAXED, __HIP_MEMORY_SCOPE_AGENT);
}
__device__ __forceinline__ void gstoreu(unsigned int* p, unsigned int v){
  __hip_atomic_store(p, v, __ATOMIC_RELAXED, __HIP_MEMORY_SCOPE_AGENT);
}
__device__ __forceinline__ unsigned int gloadu(const unsigned int* p){
  return __hip_atomic_load(p, __ATOMIC_RELAXED, __HIP_MEMORY_SCOPE_AGENT);
}

__global__ void __launch_bounds__(NTHR, 1)
ntm_kernel(Params P)
{
  const int b   = blockIdx.x;
  const int tid = threadIdx.x;
  const int wv  = tid >> 6;   // wave 0..3
  const int ln  = tid & 63;   // lane 0..63

  // ------- input pointers (setup_inputs dict order) -------
  const float* inputs  = P.in[0];
  const float* mem0    = P.in[1];
  const float* read_w0 = P.in[2];
  const float* write_w0= P.in[3];
  const float* W_ih = P.in[4];
  const float* W_hh = P.in[5];
  const float* b_ih = P.in[6];
  const float* b_hh = P.in[7];
  const float* Wo   = P.in[8];
  const float* bo   = P.in[9];
  const float* r_Wk = P.in[10]; const float* r_bk = P.in[11];
  const float* r_Wb = P.in[12]; const float* r_bb = P.in[13];
  const float* r_Wg = P.in[14]; const float* r_bg = P.in[15];
  const float* r_Ws = P.in[16]; const float* r_bs = P.in[17];
  const float* r_Wp = P.in[18]; const float* r_bp = P.in[19];
  const float* w_Wk = P.in[20]; const float* w_bk = P.in[21];
  const float* w_Wb = P.in[22]; const float* w_bb = P.in[23];
  const float* w_Wg = P.in[24]; const float* w_bg = P.in[25];
  const float* w_Ws = P.in[26]; const float* w_bs = P.in[27];
  const float* w_Wp = P.in[28]; const float* w_bp = P.in[29];
  const float* w_We = P.in[30]; const float* w_be = P.in[31];
  const float* w_Wa = P.in[32]; const float* w_ba = P.in[33];
  float* out = P.out;

  // ------- global scratch layout (floats) -------
  float* ws    = P.ws;
  float* harr  = ws;                 // 2*512 h double buffer
  float* keyw  = ws + 1024;          // 256
  float* keyr  = keyw + 256;         // 256
  float* ersv  = keyr + 256;         // 256 (post-sigmoid erase)
  float* addv  = ersv + 256;         // 256
  float* scal  = addv + 256;         // 16 raw head scalars
  float* psA   = scal + 16;          // 256 per-block partial e-sums
  float* psB   = psA + 256;          // 256 per-block partial sharpened-w sums
  float* eF    = psB + 256;          // 256 e[first row] per block
  float* eL    = eF + 256;           // 256 e[last row] per block
  float* pF    = eL + 256;           // 256 prev-w[first row] per block
  float* pL    = pF + 256;           // 256 prev-w[last row] per block
  float* parts = pL + 256;           // NG*256 rvec partial accumulators
  unsigned int* flags = (unsigned int*)(parts + NG*256); // 256 padded flags (FSTR)
  unsigned int* go    = flags + 256*FSTR;                // go epoch (own line)
  unsigned int* flg   = go + FSTR;                       // init sentinel (own line)

  // ------- LDS -------
  __shared__ float s_mem[RPB * Dsz];   // 64KB: this block's memory rows
  __shared__ float s_co[Hsz];          // staged h/co
  __shared__ float s_a[256], s_b[256], s_c[256];
  __shared__ float s_rv[256];          // current read vector
  __shared__ float s_norm[RPB];        // row norms
  __shared__ float s_e[RPB];           // content e-values (current head)
  __shared__ float s_bw[RPB];          // sharpened (unnormalized) weights
  __shared__ float s_rw[RPB];          // persistent read weights (this block's rows)
  __shared__ float s_ww[RPB];          // persistent write weights
  __shared__ float s_red[4];
  __shared__ float s_lg[8];
  __shared__ float s_wsum[4];
  __shared__ float s_cst[2];           // LSTM cell state (this block's 2 hidden units)

  unsigned int ep = 1;                 // barrier epoch

  // ------- INIT1 + handshake (ws is poisoned 0xAA each launch) -------
  {
    if (b == 0){
      gstoreu(&flags[tid * FSTR], 0u);
      if (tid == 0){ gstoreu(go, 0u); }
#pragma unroll
      for (int k = 0; k < 4; ++k) gstore(&harr[k * 256 + tid], 0.f);
    }
    if (b < NG) gstore(&parts[b * 256 + tid], 0.f);   // zero rvec parts
    if (tid < RPB){
      s_rw[tid] = read_w0[b * RPB + tid];
      s_ww[tid] = write_w0[b * RPB + tid];
    }
    if (tid < 2) s_cst[tid] = 0.f;
    __syncthreads();                     // drains each wave's stores (vmcnt 0)
    if (b == 0 && tid == 0) gstoreu(flg, 0xC0FFEEu);
    if (tid == 0){
      while (gloadu(flg) != 0xC0FFEEu) __builtin_amdgcn_s_sleep(2);
    }
    __syncthreads();
    __builtin_amdgcn_fence(__ATOMIC_ACQUIRE, "agent");
  }

  // Master/worker flag barrier.
  auto gbar = [&](){
    __syncthreads();                     // all waves' phase stores drained to LLC
    if (tid == 0) gstoreu(&flags[b * FSTR], ep);
    if (b == 0){
      if (wv == 0){
        for (;;){
          unsigned int a0 = gloadu(&flags[ln * FSTR]);
          unsigned int a1 = gloadu(&flags[(64 + ln) * FSTR]);
          unsigned int a2 = gloadu(&flags[(128 + ln) * FSTR]);
          unsigned int a3 = gloadu(&flags[(192 + ln) * FSTR]);
          bool ok = ((int)(a0 - ep) >= 0) && ((int)(a1 - ep) >= 0)
                 && ((int)(a2 - ep) >= 0) && ((int)(a3 - ep) >= 0);
          if (__all(ok)) break;
        }
        if (ln == 0) gstoreu(go, ep);
      }
    } else {
      if (tid == 0){
        while ((int)(gloadu(go) - ep) < 0) { /* one LLC load in flight */ }
      }
    }
    __syncthreads();
    __builtin_amdgcn_fence(__ATOMIC_ACQUIRE, "agent");  // invalidate, no writeback
    ++ep;
  };

  auto bred256 = [&](float v)->float{
    v = wred64(v);
    __syncthreads();
    if (ln == 0) s_red[wv] = v;
    __syncthreads();
    return s_red[0] + s_red[1] + s_red[2] + s_red[3];
  };

  // shift + sharpen for one head. Reads psA (per-block e-sums), s_e, s_prevw,
  // boundary arrays, scal[si..si+5]; writes s_bw and psB[b].
  auto shiftSharpen = [&](int si, float* s_prevw){
    float S = bred256(psA[tid]);
    float g     = sigm(scal[si + 1]);
    float gamma = softplusf(scal[si + 2]) + 1.f;
    float a0 = scal[si + 3], a1 = scal[si + 4], a2 = scal[si + 5];
    float mx = fmaxf(a0, fmaxf(a1, a2));
    float e0 = __expf(a0 - mx), e1 = __expf(a1 - mx), e2 = __expf(a2 - mx);
    float idn = 1.f / (e0 + e1 + e2);
    float s0 = e0 * idn, s1 = e1 * idn, s2 = e2 * idn;
    float invS = 1.f / S;
    float w = 0.f;
    if (tid < RPB){
      float gc = g * invS, gp = 1.f - g;
      float em = s_e[tid],  pm = s_prevw[tid];
      float e1n = (tid < RPB-1) ? s_e[tid+1]     : eF[(b + 1) & (NBLK-1)];
      float p1n = (tid < RPB-1) ? s_prevw[tid+1] : pF[(b + 1) & (NBLK-1)];
      float e2n = (tid > 0)     ? s_e[tid-1]     : eL[(b - 1) & (NBLK-1)];
      float p2n = (tid > 0)     ? s_prevw[tid-1] : pL[(b - 1) & (NBLK-1)];
      float gwm = gc * em  + gp * pm;
      float gw1 = gc * e1n + gp * p1n;   // roll(gw,-1)[m] = gw[m+1]
      float gw2 = gc * e2n + gp * p2n;   // roll(gw,+1)[m] = gw[m-1]
      float sh = s0 * gw1 + s1 * gwm + s2 * gw2;
      w = powf(sh, gamma);
      s_bw[tid] = w;
    }
    float tot = wred64(w);               // wave0 holds all 64 row values
    if (tid == 0) gstore(&psB[b], tot);
  };

  // =================== INIT2: memory rows -> LDS, norms, initial read_vec ==========
  {
#pragma unroll 1
    for (int it = 0; it < 16; ++it){
      int ml = it * 4 + wv;
      int m  = b * RPB + ml;
      float4 v = *(const float4*)(mem0 + (size_t)m * Dsz + ln * 4);
      *(float4*)(&s_mem[ml * Dsz + ln * 4]) = v;
      float n2 = v.x*v.x + v.y*v.y + v.z*v.z + v.w*v.w;
      n2 = wred64(n2);
      if (ln == 0) s_norm[ml] = sqrtf(n2);
    }
    __syncthreads();
    float acc = 0.f;
#pragma unroll 1
    for (int j = 0; j < RPB; ++j) acc += s_rw[j] * s_mem[j * Dsz + tid];
    atomicAdd(&parts[(b & (NG-1)) * 256 + tid], acc);
  }
  gbar();

  // =================== time loop ===================
  for (int t = 0; t < Tlen; ++t){
    const float* hprev = harr + (t & 1) * Hsz;
    float*       hcur  = harr + ((t + 1) & 1) * Hsz;
    const float* xt    = inputs + (size_t)t * Isz;

    // ---- A: sum rvec parts; LSTM gates GEMV + elementwise (block owns h 2b,2b+1) ----
    {
      s_co[tid] = hprev[tid]; s_co[256 + tid] = hprev[256 + tid];
      s_a[tid] = xt[tid];
      float rv = 0.f;
#pragma unroll
      for (int p = 0; p < NG; ++p) rv += parts[p * 256 + tid];
      s_rv[tid] = rv;
      __syncthreads();
      int dd = tid >> 5;          // 0..7 : (gate 0..3) x (hidden offset 0..1)
      int l  = tid & 31;
      int jj = (b << 1) + (dd & 1);
      int g  = dd >> 1;
      int r  = g * Hsz + jj;
      const float* wi = W_ih + (size_t)r * (Isz + Dsz);
      const float* wh = W_hh + (size_t)r * Hsz;
      float acc = 0.f;
#pragma unroll
      for (int it = 0; it < 4; ++it){
        int k = it * 128 + l * 4;
        float4 a  = *(const float4*)(wi + k);
        float4 x  = (k < Isz) ? *(const float4*)(&s_a[k]) : *(const float4*)(&s_rv[k - Isz]);
        acc += a.x*x.x + a.y*x.y + a.z*x.z + a.w*x.w;
        float4 hw = *(const float4*)(wh + k);
        float4 hv = *(const float4*)(&s_co[k]);
        acc += hw.x*hv.x + hw.y*hv.y + hw.z*hv.z + hw.w*hv.w;
      }
      acc = wred32(acc);
      if (l == 0) s_lg[dd] = acc + b_ih[r] + b_hh[r];
      __syncthreads();
      if (tid < 2){
        int j = (b << 1) + tid;
        float iv = s_lg[0 + tid], fv = s_lg[2 + tid], gv = s_lg[4 + tid], ov = s_lg[6 + tid];
        float cn = sigm(fv) * s_cst[tid] + sigm(iv) * tanhf(gv);
        s_cst[tid] = cn;
        gstore(&hcur[j], sigm(ov) * tanhf(cn));
      }
    }
    gbar();

    // ---- C: head projections + output GEMV (1292 dot products, 8 slots/block) ----
    {
      s_co[tid] = hcur[tid]; s_co[256 + tid] = hcur[256 + tid];
      __syncthreads();
#pragma unroll
      for (int q = 0; q < 2; ++q){
        int slot = b * 8 + wv * 2 + q;
        if (slot < 1292){
          const float* Wrow = nullptr; float bias = 0.f; int len = 512;
          float* dst = nullptr; bool act = false; bool plain = false;
          if (slot < 256){ Wrow = w_Wk + (size_t)slot * Hsz; bias = w_bk[slot]; dst = keyw + slot; }
          else if (slot < 512){ int i = slot - 256; Wrow = w_We + (size_t)i * Hsz; bias = w_be[i]; dst = ersv + i; act = true; }
          else if (slot < 768){ int i = slot - 512; Wrow = w_Wa + (size_t)i * Hsz; bias = w_ba[i]; dst = addv + i; }
          else if (slot < 1024){ int i = slot - 768; Wrow = r_Wk + (size_t)i * Hsz; bias = r_bk[i]; dst = keyr + i; }
          else if (slot < 1280){ int i = slot - 1024; Wrow = Wo + (size_t)i * (Hsz + Dsz); bias = bo[i]; len = 768; dst = out + (size_t)t * Isz + i; plain = true; }
          else {
            int i = slot - 1280;
            int ii = (i >= 6) ? i - 6 : i;
            bool rh = (i >= 6);
            const float *Wt, *bt; int row = 0;
            if (ii == 0){ Wt = rh ? r_Wb : w_Wb; bt = rh ? r_bb : w_bb; }
            else if (ii == 1){ Wt = rh ? r_Wg : w_Wg; bt = rh ? r_bg : w_bg; }
            else if (ii == 2){ Wt = rh ? r_Wp : w_Wp; bt = rh ? r_bp : w_bp; }
            else { Wt = rh ? r_Ws : w_Ws; bt = rh ? r_bs : w_bs; row = ii - 3; }
            Wrow = Wt + (size_t)row * Hsz; bias = bt[row]; dst = scal + i;
          }
          float acc = 0.f;
          if (len == 512){
            int k = ln * 8;
            float4 a0 = *(const float4*)(Wrow + k);
            float4 a1 = *(const float4*)(Wrow + k + 4);
            float4 c0 = *(const float4*)(&s_co[k]);
            float4 c1 = *(const float4*)(&s_co[k + 4]);
            acc = a0.x*c0.x + a0.y*c0.y + a0.z*c0.z + a0.w*c0.w
                + a1.x*c1.x + a1.y*c1.y + a1.z*c1.z + a1.w*c1.w;
          } else {
#pragma unroll 1
            for (int kk = ln; kk < 768; kk += 64){
              float x = (kk < Hsz) ? s_co[kk] : s_rv[kk - Hsz];
              acc += Wrow[kk] * x;
            }
          }
          acc = wred64(acc);
          if (ln == 0){
            float v = acc + bias;
            if (act) v = sigm(v);
            if (plain) *dst = v; else gstore(dst, v);
          }
        }
      }
    }
    gbar();

    // ---- D: write-head content scores -> s_e = exp(beta*(cos-1)); publish sums+bounds ----
    {
      s_a[tid] = keyw[tid];
      float nk2 = bred256(s_a[tid] * s_a[tid]);
      float beta  = softplusf(scal[0]);
      float invbk = beta / fmaxf(sqrtf(nk2), 1e-12f);
      float esum = 0.f;
#pragma unroll 1
      for (int it = 0; it < 16; ++it){
        int ml = it * 4 + wv;
        float4 v  = *(const float4*)(&s_mem[ml * Dsz + ln * 4]);
        float4 kv = *(const float4*)(&s_a[ln * 4]);
        float d = v.x*kv.x + v.y*kv.y + v.z*kv.z + v.w*kv.w;
        d = wred64(d);
        float score = d * invbk / fmaxf(s_norm[ml], 1e-12f);
        float e = __expf(score - beta);
        if (ln == 0){ s_e[ml] = e; esum += e; }
      }
      if (ln == 0) s_wsum[wv] = esum;
      __syncthreads();
      if (tid == 0){
        gstore(&psA[b], s_wsum[0] + s_wsum[1] + s_wsum[2] + s_wsum[3]);
        gstore(&eF[b], s_e[0]);  gstore(&eL[b], s_e[RPB-1]);
        gstore(&pF[b], s_ww[0]); gstore(&pL[b], s_ww[RPB-1]);
      }
    }
    gbar();

    // ---- F: write-head interpolate + shift + sharpen; zero rvec parts for this step ----
    shiftSharpen(0, s_ww);
    if (b < NG) gstore(&parts[b * 256 + tid], 0.f);
    gbar();

    // ---- H: normalize ww, memory erase/add update (LDS), new norms + read-head scores ----
    {
      s_a[tid] = ersv[tid]; s_b[tid] = addv[tid]; s_c[tid] = keyr[tid];
      float nk2 = bred256(s_c[tid] * s_c[tid]);
      float beta  = softplusf(scal[6]);
      float invbk = beta / fmaxf(sqrtf(nk2), 1e-12f);
      float Sw = bred256(psB[tid]);
      float invSw = 1.f / (Sw + 1e-8f);
      if (tid < RPB) s_ww[tid] = s_bw[tid] * invSw;   // persist normalized write weights
      float esum = 0.f;
#pragma unroll 1
      for (int it = 0; it < 16; ++it){
        int ml = it * 4 + wv;
        float wwm = s_bw[ml] * invSw;
        int off = ml * Dsz + ln * 4;
        float4 mv = *(const float4*)(&s_mem[off]);
        float4 er = *(const float4*)(&s_a[ln * 4]);
        float4 ad = *(const float4*)(&s_b[ln * 4]);
        float4 kr = *(const float4*)(&s_c[ln * 4]);
        float4 nv;
        nv.x = mv.x * (1.f - wwm * er.x) + wwm * ad.x;
        nv.y = mv.y * (1.f - wwm * er.y) + wwm * ad.y;
        nv.z = mv.z * (1.f - wwm * er.z) + wwm * ad.z;
        nv.w = mv.w * (1.f - wwm * er.w) + wwm * ad.w;
        *(float4*)(&s_mem[off]) = nv;
        float n2 = nv.x*nv.x + nv.y*nv.y + nv.z*nv.z + nv.w*nv.w;
        float dt = nv.x*kr.x + nv.y*kr.y + nv.z*kr.z + nv.w*kr.w;
        n2 = wred64(n2);
        dt = wred64(dt);
        float nr = sqrtf(n2);
        if (ln == 0) s_norm[ml] = nr;
        float score = dt * invbk / fmaxf(nr, 1e-12f);
        float e = __expf(score - beta);
        if (ln == 0){ s_e[ml] = e; esum += e; }
      }
      if (ln == 0) s_wsum[wv] = esum;
      __syncthreads();
      if (tid == 0){
        gstore(&psA[b], s_wsum[0] + s_wsum[1] + s_wsum[2] + s_wsum[3]);
        gstore(&eF[b], s_e[0]);  gstore(&eL[b], s_e[RPB-1]);
        gstore(&pF[b], s_rw[0]); gstore(&pL[b], s_rw[RPB-1]);
      }
    }
    gbar();

    // ---- J: read-head interpolate + shift + sharpen ----
    shiftSharpen(6, s_rw);
    gbar();

    // ---- L: normalize rw, accumulate next read_vec = rw_new @ mem_new ----
    {
      float Sr = bred256(psB[tid]);
      float invSr = 1.f / (Sr + 1e-8f);
      if (tid < RPB) s_rw[tid] = s_bw[tid] * invSr;
      __syncthreads();
      float acc = 0.f;
#pragma unroll 1
      for (int j = 0; j < RPB; ++j) acc += s_rw[j] * s_mem[j * Dsz + tid];
      atomicAdd(&parts[(b & (NG-1)) * 256 + tid], acc);
    }
    gbar();
  }
}

extern "C" void kernel_launch(void* const* d_in, const int* in_sizes, int n_in,
                              void* d_out, int out_size, void* d_ws, size_t ws_size,
                              hipStream_t stream)
{
  (void)in_sizes; (void)out_size;
  if (n_in < 34) return;
  if (ws_size < (size_t)131072) return;   // ~96KB scratch needed; require 128KB
  Params P;
  for (int i = 0; i < 34; ++i) P.in[i] = (const float*)d_in[i];
  P.out = (float*)d_out;
  P.ws  = (float*)d_ws;
  hipLaunchKernelGGL(ntm_kernel, dim3(NBLK), dim3(NTHR), 0, stream, P);
}

// Round 6
// 5198.330 us; speedup vs baseline: 4.1838x; 2.4001x over previous
//
#include <hip/hip_runtime.h>
#include <math.h>

// Persistent-kernel NTM, R6: NO acquire fences at all.
// - All mutable cross-block data (flags, go, h, keys, scalars, partial sums)
//   is accessed exclusively with agent-scope relaxed atomic (sc1) load/store:
//   always coherent at the LLC, no L2 invalidate needed.
// - Read-only data (weights, inputs, mem0) uses plain loads -> stays hot in
//   per-XCD L2 across all 128 timesteps (no buffer_inv evictions).
// - Barrier: arrival flags on own cachelines; master (block 0, wave 0) polls;
//   go epoch replicated on 8 cachelines (32 pollers each); s_sleep backoff.
// 7 grid barriers per timestep x 128 steps.

#define NBLK 256
#define NTHR 256
#define Msz  16384
#define Dsz  256
#define Hsz  512
#define Isz  256
#define Tlen 128
#define RPB  64    // memory rows per block
#define NG   8     // rvec atomic groups
#define FSTR 32    // flag stride in uints (128B line)

struct Params {
  const float* in[34];
  float* out;
  float* ws;
};

__device__ __forceinline__ float wred64(float v){
#pragma unroll
  for (int o = 32; o > 0; o >>= 1) v += __shfl_xor(v, o, 64);
  return v;
}
__device__ __forceinline__ float wred32(float v){
#pragma unroll
  for (int o = 16; o > 0; o >>= 1) v += __shfl_xor(v, o, 32);
  return v;
}
__device__ __forceinline__ float sigm(float x){ return 1.f / (1.f + __expf(-x)); }
__device__ __forceinline__ float softplusf(float x){ return (x > 20.f) ? x : log1pf(__expf(x)); }

// agent-scope (LLC-coherent) accessors for mutable cross-block data
__device__ __forceinline__ void gstore(float* p, float v){
  __hip_atomic_store(p, v, __ATOMIC_RELAXED, __HIP_MEMORY_SCOPE_AGENT);
}
__device__ __forceinline__ float gload(const float* p){
  return __hip_atomic_load(p, __ATOMIC_RELAXED, __HIP_MEMORY_SCOPE_AGENT);
}
__device__ __forceinline__ void gstoreu(unsigned int* p, unsigned int v){
  __hip_atomic_store(p, v, __ATOMIC_RELAXED, __HIP_MEMORY_SCOPE_AGENT);
}
__device__ __forceinline__ unsigned int gloadu(const unsigned int* p){
  return __hip_atomic_load(p, __ATOMIC_RELAXED, __HIP_MEMORY_SCOPE_AGENT);
}

__global__ void __launch_bounds__(NTHR, 1)
ntm_kernel(Params P)
{
  const int b   = blockIdx.x;
  const int tid = threadIdx.x;
  const int wv  = tid >> 6;   // wave 0..3
  const int ln  = tid & 63;   // lane 0..63

  // ------- input pointers (setup_inputs dict order) -------
  const float* inputs  = P.in[0];
  const float* mem0    = P.in[1];
  const float* read_w0 = P.in[2];
  const float* write_w0= P.in[3];
  const float* W_ih = P.in[4];
  const float* W_hh = P.in[5];
  const float* b_ih = P.in[6];
  const float* b_hh = P.in[7];
  const float* Wo   = P.in[8];
  const float* bo   = P.in[9];
  const float* r_Wk = P.in[10]; const float* r_bk = P.in[11];
  const float* r_Wb = P.in[12]; const float* r_bb = P.in[13];
  const float* r_Wg = P.in[14]; const float* r_bg = P.in[15];
  const float* r_Ws = P.in[16]; const float* r_bs = P.in[17];
  const float* r_Wp = P.in[18]; const float* r_bp = P.in[19];
  const float* w_Wk = P.in[20]; const float* w_bk = P.in[21];
  const float* w_Wb = P.in[22]; const float* w_bb = P.in[23];
  const float* w_Wg = P.in[24]; const float* w_bg = P.in[25];
  const float* w_Ws = P.in[26]; const float* w_bs = P.in[27];
  const float* w_Wp = P.in[28]; const float* w_bp = P.in[29];
  const float* w_We = P.in[30]; const float* w_be = P.in[31];
  const float* w_Wa = P.in[32]; const float* w_ba = P.in[33];
  float* out = P.out;

  // ------- global scratch layout (floats) -------
  float* ws    = P.ws;
  float* harr  = ws;                 // 2*512 h double buffer
  float* keyw  = ws + 1024;          // 256
  float* keyr  = keyw + 256;         // 256
  float* ersv  = keyr + 256;         // 256 (post-sigmoid erase)
  float* addv  = ersv + 256;         // 256
  float* scal  = addv + 256;         // 16 raw head scalars
  float* psA   = scal + 16;          // 256 per-block partial e-sums
  float* psB   = psA + 256;          // 256 per-block partial sharpened-w sums
  float* eF    = psB + 256;          // 256 e[first row] per block
  float* eL    = eF + 256;           // 256 e[last row] per block
  float* pF    = eL + 256;           // 256 prev-w[first row] per block
  float* pL    = pF + 256;           // 256 prev-w[last row] per block
  float* parts = pL + 256;           // NG*256 rvec partial accumulators
  unsigned int* flags = (unsigned int*)(parts + NG*256); // 256 padded flags (FSTR)
  unsigned int* go    = flags + 256*FSTR;                // 8 replicated go lines
  unsigned int* flg   = go + 8*FSTR;                     // init sentinel (own line)

  // ------- LDS -------
  __shared__ float s_mem[RPB * Dsz];   // 64KB: this block's memory rows
  __shared__ float s_co[Hsz];          // staged h/co
  __shared__ float s_a[256], s_b[256], s_c[256];
  __shared__ float s_rv[256];          // current read vector
  __shared__ float s_norm[RPB];        // row norms
  __shared__ float s_e[RPB];           // content e-values (current head)
  __shared__ float s_bw[RPB];          // sharpened (unnormalized) weights
  __shared__ float s_rw[RPB];          // persistent read weights (this block's rows)
  __shared__ float s_ww[RPB];          // persistent write weights
  __shared__ float s_red[4];
  __shared__ float s_lg[8];
  __shared__ float s_wsum[4];
  __shared__ float s_cst[2];           // LSTM cell state (this block's 2 hidden units)

  unsigned int ep = 1;                 // barrier epoch

  // ------- INIT1 + handshake (ws is poisoned 0xAA each launch) -------
  {
    if (b == 0){
      gstoreu(&flags[tid * FSTR], 0u);
      if (tid < 8) gstoreu(&go[tid * FSTR], 0u);
#pragma unroll
      for (int k = 0; k < 4; ++k) gstore(&harr[k * 256 + tid], 0.f);
    }
    if (b < NG) gstore(&parts[b * 256 + tid], 0.f);   // zero rvec parts
    if (tid < RPB){
      s_rw[tid] = read_w0[b * RPB + tid];
      s_ww[tid] = write_w0[b * RPB + tid];
    }
    if (tid < 2) s_cst[tid] = 0.f;
    __syncthreads();                     // drains each wave's stores (vmcnt 0)
    if (b == 0 && tid == 0) gstoreu(flg, 0xC0FFEEu);
    if (tid == 0){
      while (gloadu(flg) != 0xC0FFEEu) __builtin_amdgcn_s_sleep(2);
    }
    __syncthreads();
  }

  // Master/worker flag barrier (no fences; sync data all sc1).
  auto gbar = [&](){
    __syncthreads();                     // all waves' sc1 stores drained to LLC
    if (tid == 0) gstoreu(&flags[b * FSTR], ep);
    if (b == 0){
      if (wv == 0){
        for (;;){
          unsigned int a0 = gloadu(&flags[ln * FSTR]);
          unsigned int a1 = gloadu(&flags[(64 + ln) * FSTR]);
          unsigned int a2 = gloadu(&flags[(128 + ln) * FSTR]);
          unsigned int a3 = gloadu(&flags[(192 + ln) * FSTR]);
          bool ok = ((int)(a0 - ep) >= 0) && ((int)(a1 - ep) >= 0)
                 && ((int)(a2 - ep) >= 0) && ((int)(a3 - ep) >= 0);
          if (__all(ok)) break;
          __builtin_amdgcn_s_sleep(1);
        }
        if (ln < 8) gstoreu(&go[ln * FSTR], ep);
      }
    } else {
      if (tid == 0){
        unsigned int* myGo = &go[(b & 7) * FSTR];
        while ((int)(gloadu(myGo) - ep) < 0) __builtin_amdgcn_s_sleep(1);
      }
    }
    __syncthreads();
    ++ep;
  };

  auto bred256 = [&](float v)->float{
    v = wred64(v);
    __syncthreads();
    if (ln == 0) s_red[wv] = v;
    __syncthreads();
    return s_red[0] + s_red[1] + s_red[2] + s_red[3];
  };

  // shift + sharpen for one head. Reads psA (per-block e-sums), s_e, s_prevw,
  // boundary arrays, scal[si..si+5]; writes s_bw and psB[b].
  auto shiftSharpen = [&](int si, float* s_prevw){
    float S = bred256(gload(&psA[tid]));
    float g     = sigm(gload(&scal[si + 1]));
    float gamma = softplusf(gload(&scal[si + 2])) + 1.f;
    float a0 = gload(&scal[si + 3]), a1 = gload(&scal[si + 4]), a2 = gload(&scal[si + 5]);
    float mx = fmaxf(a0, fmaxf(a1, a2));
    float e0 = __expf(a0 - mx), e1 = __expf(a1 - mx), e2 = __expf(a2 - mx);
    float idn = 1.f / (e0 + e1 + e2);
    float s0 = e0 * idn, s1 = e1 * idn, s2 = e2 * idn;
    float invS = 1.f / S;
    float w = 0.f;
    if (tid < RPB){
      float gc = g * invS, gp = 1.f - g;
      float em = s_e[tid],  pm = s_prevw[tid];
      float e1n = (tid < RPB-1) ? s_e[tid+1]     : gload(&eF[(b + 1) & (NBLK-1)]);
      float p1n = (tid < RPB-1) ? s_prevw[tid+1] : gload(&pF[(b + 1) & (NBLK-1)]);
      float e2n = (tid > 0)     ? s_e[tid-1]     : gload(&eL[(b - 1) & (NBLK-1)]);
      float p2n = (tid > 0)     ? s_prevw[tid-1] : gload(&pL[(b - 1) & (NBLK-1)]);
      float gwm = gc * em  + gp * pm;
      float gw1 = gc * e1n + gp * p1n;   // roll(gw,-1)[m] = gw[m+1]
      float gw2 = gc * e2n + gp * p2n;   // roll(gw,+1)[m] = gw[m-1]
      float sh = s0 * gw1 + s1 * gwm + s2 * gw2;
      w = powf(sh, gamma);
      s_bw[tid] = w;
    }
    float tot = wred64(w);               // wave0 holds all 64 row values
    if (tid == 0) gstore(&psB[b], tot);
  };

  // =================== INIT2: memory rows -> LDS, norms, initial read_vec ==========
  {
#pragma unroll 1
    for (int it = 0; it < 16; ++it){
      int ml = it * 4 + wv;
      int m  = b * RPB + ml;
      float4 v = *(const float4*)(mem0 + (size_t)m * Dsz + ln * 4);
      *(float4*)(&s_mem[ml * Dsz + ln * 4]) = v;
      float n2 = v.x*v.x + v.y*v.y + v.z*v.z + v.w*v.w;
      n2 = wred64(n2);
      if (ln == 0) s_norm[ml] = sqrtf(n2);
    }
    __syncthreads();
    float acc = 0.f;
#pragma unroll 1
    for (int j = 0; j < RPB; ++j) acc += s_rw[j] * s_mem[j * Dsz + tid];
    atomicAdd(&parts[(b & (NG-1)) * 256 + tid], acc);
  }
  gbar();

  // =================== time loop ===================
  for (int t = 0; t < Tlen; ++t){
    const float* hprev = harr + (t & 1) * Hsz;
    float*       hcur  = harr + ((t + 1) & 1) * Hsz;
    const float* xt    = inputs + (size_t)t * Isz;

    // ---- A: sum rvec parts; LSTM gates GEMV + elementwise (block owns h 2b,2b+1) ----
    {
      s_co[tid] = gload(&hprev[tid]); s_co[256 + tid] = gload(&hprev[256 + tid]);
      s_a[tid] = xt[tid];
      float rv = 0.f;
#pragma unroll
      for (int p = 0; p < NG; ++p) rv += gload(&parts[p * 256 + tid]);
      s_rv[tid] = rv;
      __syncthreads();
      int dd = tid >> 5;          // 0..7 : (gate 0..3) x (hidden offset 0..1)
      int l  = tid & 31;
      int jj = (b << 1) + (dd & 1);
      int g  = dd >> 1;
      int r  = g * Hsz + jj;
      const float* wi = W_ih + (size_t)r * (Isz + Dsz);
      const float* wh = W_hh + (size_t)r * Hsz;
      float acc = 0.f;
#pragma unroll
      for (int it = 0; it < 4; ++it){
        int k = it * 128 + l * 4;
        float4 a  = *(const float4*)(wi + k);
        float4 x  = (k < Isz) ? *(const float4*)(&s_a[k]) : *(const float4*)(&s_rv[k - Isz]);
        acc += a.x*x.x + a.y*x.y + a.z*x.z + a.w*x.w;
        float4 hw = *(const float4*)(wh + k);
        float4 hv = *(const float4*)(&s_co[k]);
        acc += hw.x*hv.x + hw.y*hv.y + hw.z*hv.z + hw.w*hv.w;
      }
      acc = wred32(acc);
      if (l == 0) s_lg[dd] = acc + b_ih[r] + b_hh[r];
      __syncthreads();
      if (tid < 2){
        int j = (b << 1) + tid;
        float iv = s_lg[0 + tid], fv = s_lg[2 + tid], gv = s_lg[4 + tid], ov = s_lg[6 + tid];
        float cn = sigm(fv) * s_cst[tid] + sigm(iv) * tanhf(gv);
        s_cst[tid] = cn;
        gstore(&hcur[j], sigm(ov) * tanhf(cn));
      }
    }
    gbar();

    // ---- C: head projections + output GEMV (1292 dot products, 8 slots/block) ----
    {
      s_co[tid] = gload(&hcur[tid]); s_co[256 + tid] = gload(&hcur[256 + tid]);
      __syncthreads();
#pragma unroll
      for (int q = 0; q < 2; ++q){
        int slot = b * 8 + wv * 2 + q;
        if (slot < 1292){
          const float* Wrow = nullptr; float bias = 0.f; int len = 512;
          float* dst = nullptr; bool act = false; bool plain = false;
          if (slot < 256){ Wrow = w_Wk + (size_t)slot * Hsz; bias = w_bk[slot]; dst = keyw + slot; }
          else if (slot < 512){ int i = slot - 256; Wrow = w_We + (size_t)i * Hsz; bias = w_be[i]; dst = ersv + i; act = true; }
          else if (slot < 768){ int i = slot - 512; Wrow = w_Wa + (size_t)i * Hsz; bias = w_ba[i]; dst = addv + i; }
          else if (slot < 1024){ int i = slot - 768; Wrow = r_Wk + (size_t)i * Hsz; bias = r_bk[i]; dst = keyr + i; }
          else if (slot < 1280){ int i = slot - 1024; Wrow = Wo + (size_t)i * (Hsz + Dsz); bias = bo[i]; len = 768; dst = out + (size_t)t * Isz + i; plain = true; }
          else {
            int i = slot - 1280;
            int ii = (i >= 6) ? i - 6 : i;
            bool rh = (i >= 6);
            const float *Wt, *bt; int row = 0;
            if (ii == 0){ Wt = rh ? r_Wb : w_Wb; bt = rh ? r_bb : w_bb; }
            else if (ii == 1){ Wt = rh ? r_Wg : w_Wg; bt = rh ? r_bg : w_bg; }
            else if (ii == 2){ Wt = rh ? r_Wp : w_Wp; bt = rh ? r_bp : w_bp; }
            else { Wt = rh ? r_Ws : w_Ws; bt = rh ? r_bs : w_bs; row = ii - 3; }
            Wrow = Wt + (size_t)row * Hsz; bias = bt[row]; dst = scal + i;
          }
          float acc = 0.f;
          if (len == 512){
            int k = ln * 8;
            float4 a0 = *(const float4*)(Wrow + k);
            float4 a1 = *(const float4*)(Wrow + k + 4);
            float4 c0 = *(const float4*)(&s_co[k]);
            float4 c1 = *(const float4*)(&s_co[k + 4]);
            acc = a0.x*c0.x + a0.y*c0.y + a0.z*c0.z + a0.w*c0.w
                + a1.x*c1.x + a1.y*c1.y + a1.z*c1.z + a1.w*c1.w;
          } else {
#pragma unroll 1
            for (int kk = ln; kk < 768; kk += 64){
              float x = (kk < Hsz) ? s_co[kk] : s_rv[kk - Hsz];
              acc += Wrow[kk] * x;
            }
          }
          acc = wred64(acc);
          if (ln == 0){
            float v = acc + bias;
            if (act) v = sigm(v);
            if (plain) *dst = v; else gstore(dst, v);
          }
        }
      }
    }
    gbar();

    // ---- D: write-head content scores -> s_e = exp(beta*(cos-1)); publish sums+bounds ----
    {
      s_a[tid] = gload(&keyw[tid]);
      float nk2 = bred256(s_a[tid] * s_a[tid]);
      float beta  = softplusf(gload(&scal[0]));
      float invbk = beta / fmaxf(sqrtf(nk2), 1e-12f);
      float esum = 0.f;
#pragma unroll 1
      for (int it = 0; it < 16; ++it){
        int ml = it * 4 + wv;
        float4 v  = *(const float4*)(&s_mem[ml * Dsz + ln * 4]);
        float4 kv = *(const float4*)(&s_a[ln * 4]);
        float d = v.x*kv.x + v.y*kv.y + v.z*kv.z + v.w*kv.w;
        d = wred64(d);
        float score = d * invbk / fmaxf(s_norm[ml], 1e-12f);
        float e = __expf(score - beta);
        if (ln == 0){ s_e[ml] = e; esum += e; }
      }
      if (ln == 0) s_wsum[wv] = esum;
      __syncthreads();
      if (tid == 0){
        gstore(&psA[b], s_wsum[0] + s_wsum[1] + s_wsum[2] + s_wsum[3]);
        gstore(&eF[b], s_e[0]);  gstore(&eL[b], s_e[RPB-1]);
        gstore(&pF[b], s_ww[0]); gstore(&pL[b], s_ww[RPB-1]);
      }
    }
    gbar();

    // ---- F: write-head interpolate + shift + sharpen; zero rvec parts for this step ----
    shiftSharpen(0, s_ww);
    if (b < NG) gstore(&parts[b * 256 + tid], 0.f);
    gbar();

    // ---- H: normalize ww, memory erase/add update (LDS), new norms + read-head scores ----
    {
      s_a[tid] = gload(&ersv[tid]); s_b[tid] = gload(&addv[tid]); s_c[tid] = gload(&keyr[tid]);
      float nk2 = bred256(s_c[tid] * s_c[tid]);
      float beta  = softplusf(gload(&scal[6]));
      float invbk = beta / fmaxf(sqrtf(nk2), 1e-12f);
      float Sw = bred256(gload(&psB[tid]));
      float invSw = 1.f / (Sw + 1e-8f);
      if (tid < RPB) s_ww[tid] = s_bw[tid] * invSw;   // persist normalized write weights
      float esum = 0.f;
#pragma unroll 1
      for (int it = 0; it < 16; ++it){
        int ml = it * 4 + wv;
        float wwm = s_bw[ml] * invSw;
        int off = ml * Dsz + ln * 4;
        float4 mv = *(const float4*)(&s_mem[off]);
        float4 er = *(const float4*)(&s_a[ln * 4]);
        float4 ad = *(const float4*)(&s_b[ln * 4]);
        float4 kr = *(const float4*)(&s_c[ln * 4]);
        float4 nv;
        nv.x = mv.x * (1.f - wwm * er.x) + wwm * ad.x;
        nv.y = mv.y * (1.f - wwm * er.y) + wwm * ad.y;
        nv.z = mv.z * (1.f - wwm * er.z) + wwm * ad.z;
        nv.w = mv.w * (1.f - wwm * er.w) + wwm * ad.w;
        *(float4*)(&s_mem[off]) = nv;
        float n2 = nv.x*nv.x + nv.y*nv.y + nv.z*nv.z + nv.w*nv.w;
        float dt = nv.x*kr.x + nv.y*kr.y + nv.z*kr.z + nv.w*kr.w;
        n2 = wred64(n2);
        dt = wred64(dt);
        float nr = sqrtf(n2);
        if (ln == 0) s_norm[ml] = nr;
        float score = dt * invbk / fmaxf(nr, 1e-12f);
        float e = __expf(score - beta);
        if (ln == 0){ s_e[ml] = e; esum += e; }
      }
      if (ln == 0) s_wsum[wv] = esum;
      __syncthreads();
      if (tid == 0){
        gstore(&psA[b], s_wsum[0] + s_wsum[1] + s_wsum[2] + s_wsum[3]);
        gstore(&eF[b], s_e[0]);  gstore(&eL[b], s_e[RPB-1]);
        gstore(&pF[b], s_rw[0]); gstore(&pL[b], s_rw[RPB-1]);
      }
    }
    gbar();

    // ---- J: read-head interpolate + shift + sharpen ----
    shiftSharpen(6, s_rw);
    gbar();

    // ---- L: normalize rw, accumulate next read_vec = rw_new @ mem_new ----
    {
      float Sr = bred256(gload(&psB[tid]));
      float invSr = 1.f / (Sr + 1e-8f);
      if (tid < RPB) s_rw[tid] = s_bw[tid] * invSr;
      __syncthreads();
      float acc = 0.f;
#pragma unroll 1
      for (int j = 0; j < RPB; ++j) acc += s_rw[j] * s_mem[j * Dsz + tid];
      atomicAdd(&parts[(b & (NG-1)) * 256 + tid], acc);
    }
    gbar();
  }
}

extern "C" void kernel_launch(void* const* d_in, const int* in_sizes, int n_in,
                              void* d_out, int out_size, void* d_ws, size_t ws_size,
                              hipStream_t stream)
{
  (void)in_sizes; (void)out_size;
  if (n_in < 34) return;
  if (ws_size < (size_t)131072) return;   // ~60KB scratch needed; require 128KB
  Params P;
  for (int i = 0; i < 34; ++i) P.in[i] = (const float*)d_in[i];
  P.out = (float*)d_out;
  P.ws  = (float*)d_ws;
  hipLaunchKernelGGL(ntm_kernel, dim3(NBLK), dim3(NTHR), 0, stream, P);
}